// Round 1
// baseline (100.431 us; speedup 1.0000x reference)
//
#include <hip/hip_runtime.h>
#include <cstdint>
#include <cstddef>

typedef __attribute__((ext_vector_type(8))) short short8;
typedef __attribute__((ext_vector_type(4))) short short4v;
typedef __attribute__((ext_vector_type(4))) float f32x4;
typedef short8 bf16x8;

typedef __attribute__((address_space(1))) const unsigned GU;
typedef __attribute__((address_space(3))) unsigned LU;

__device__ __forceinline__ short f2bf(float f) {
  unsigned u = __builtin_bit_cast(unsigned, f);
  u += 0x7fffu + ((u >> 16) & 1u);   // RNE; inputs are finite normals
  return (short)(u >> 16);
}

// ---------------- cast x (f32 -> bf16) ----------------
__global__ __launch_bounds__(256) void k_cast_x(const float* __restrict__ x, short* __restrict__ xb) {
  size_t i = ((size_t)blockIdx.x * 256 + threadIdx.x) * 8;
  f32x4 a = *(const f32x4*)(x + i);
  f32x4 b = *(const f32x4*)(x + i + 4);
  short8 o;
#pragma unroll
  for (int j = 0; j < 4; ++j) { o[j] = f2bf(a[j]); o[4 + j] = f2bf(b[j]); }
  *(short8*)(xb + i) = o;
}

// ---------------- cast + transpose weights: WT[n][k] = W[k][n] (bf16) ----------------
__global__ __launch_bounds__(256) void k_tw(const float* __restrict__ W0, const float* __restrict__ W1,
                                            const float* __restrict__ W2, const float* __restrict__ W3,
                                            short* __restrict__ WT) {
  __shared__ short T[64 * 72];
  int bid = blockIdx.x;
  int widx = bid >> 8;
  int t = bid & 255;
  int kr = (t >> 4) * 64, nc = (t & 15) * 64;
  const float* W = widx == 0 ? W0 : widx == 1 ? W1 : widx == 2 ? W2 : W3;
  short* out = WT + (size_t)widx * 1048576;
  int tid = threadIdx.x;
#pragma unroll
  for (int i = 0; i < 4; ++i) {
    int idx = tid + i * 256;          // 1024 quads of 4 floats
    int k = idx >> 4, n4 = (idx & 15) << 2;
    f32x4 v = *(const f32x4*)(W + (size_t)(kr + k) * 1024 + nc + n4);
#pragma unroll
    for (int j = 0; j < 4; ++j) T[(n4 + j) * 72 + k] = f2bf(v[j]);
  }
  __syncthreads();
#pragma unroll
  for (int i = 0; i < 2; ++i) {
    int idx = tid + i * 256;
    int n = idx >> 3, k8 = (idx & 7) << 3;
    *(short8*)(out + (size_t)(nc + n) * 1024 + kr + k8) = *(const short8*)&T[n * 72 + k8];
  }
}

// ---------------- transpose v: vT[b][h][d][s] = v[b][s][h*64+d] ----------------
__global__ __launch_bounds__(256) void k_tv(const short* __restrict__ v, short* __restrict__ vT) {
  __shared__ short T[64 * 72];
  int bid = blockIdx.x;
  int stile = bid & 31, h = (bid >> 5) & 15, b = bid >> 9;
  int s0 = stile * 64;
  int tid = threadIdx.x;
#pragma unroll
  for (int i = 0; i < 2; ++i) {
    int idx = tid + i * 256;
    int s = idx >> 3, d0 = (idx & 7) << 3;
    short8 vec = *(const short8*)(v + ((size_t)b * 2048 + s0 + s) * 1024 + h * 64 + d0);
#pragma unroll
    for (int j = 0; j < 8; ++j) T[(d0 + j) * 72 + s] = vec[j];
  }
  __syncthreads();
#pragma unroll
  for (int i = 0; i < 2; ++i) {
    int idx = tid + i * 256;
    int d = idx >> 3, s8 = (idx & 7) << 3;
    *(short8*)(vT + (((size_t)b * 16 + h) * 64 + d) * 2048 + s0 + s8) = *(const short8*)&T[d * 72 + s8];
  }
}

// ---------------- GEMM: C[M,N] = A[M,K] * BT[N,K]^T  (bf16 in, fp32 accum) ----------------
// MODE 0: bf16 out into qkv buffers (N=3072, bias select per 1024-col group)
// MODE 1: fp32 out (+bias0) into d_out (N=1024)
template <int MODE>
__global__ __launch_bounds__(256, 2) void k_gemm(
    const short* __restrict__ A, const short* __restrict__ BT,
    const float* __restrict__ bias0, const float* __restrict__ bias1, const float* __restrict__ bias2,
    short* __restrict__ outb, float* __restrict__ outf) {
  __shared__ short As[2][128 * 32];
  __shared__ short Bs[2][128 * 32];
  const int tid = threadIdx.x;
  const int lane = tid & 63, w = tid >> 6;
  const int g = lane >> 4, qi = lane & 15;
  const int wr = (w >> 1) * 64, wc = (w & 1) * 64;
  const int m0 = blockIdx.y * 128, n0 = blockIdx.x * 128;
  const size_t K = 1024;
  const short* Ab = A + (size_t)m0 * K;
  const short* Bb = BT + (size_t)n0 * K;

  auto stage = [&](int buf, int k0) {
#pragma unroll
    for (int i = 0; i < 2; ++i) {
      int cidx = tid + i * 256;               // 512 chunks of 8 bf16 per tile
      int r = cidx >> 2, c = (cidx & 3) << 3; // linear LDS [128][32]
      __builtin_amdgcn_global_load_lds((GU*)(Ab + (size_t)r * K + k0 + c),
                                       (LU*)(&As[buf][cidx * 8]), 16, 0, 0);
      __builtin_amdgcn_global_load_lds((GU*)(Bb + (size_t)r * K + k0 + c),
                                       (LU*)(&Bs[buf][cidx * 8]), 16, 0, 0);
    }
  };

  f32x4 acc[4][4];
#pragma unroll
  for (int i = 0; i < 4; ++i)
#pragma unroll
    for (int j = 0; j < 4; ++j) acc[i][j] = (f32x4)(0.0f);

  stage(0, 0);
  __syncthreads();
  for (int kt = 0; kt < 32; ++kt) {
    int cur = kt & 1;
    if (kt < 31) stage(cur ^ 1, (kt + 1) * 32);
    bf16x8 a[4], b[4];
#pragma unroll
    for (int mf = 0; mf < 4; ++mf)
      a[mf] = *(const bf16x8*)&As[cur][(wr + mf * 16 + qi) * 32 + g * 8];
#pragma unroll
    for (int nf = 0; nf < 4; ++nf)
      b[nf] = *(const bf16x8*)&Bs[cur][(wc + nf * 16 + qi) * 32 + g * 8];
#pragma unroll
    for (int mf = 0; mf < 4; ++mf)
#pragma unroll
      for (int nf = 0; nf < 4; ++nf)
        acc[mf][nf] = __builtin_amdgcn_mfma_f32_16x16x32_bf16(a[mf], b[nf], acc[mf][nf], 0, 0, 0);
    __syncthreads();
  }

  if (MODE == 0) {
    int sel = n0 >> 10;
    const float* bias = sel == 0 ? bias0 : (sel == 1 ? bias1 : bias2);
    size_t outoff = (size_t)sel * 4194304;
#pragma unroll
    for (int nf = 0; nf < 4; ++nf) {
      int col = n0 + wc + nf * 16 + qi;
      int cl = col & 1023;
      float bv = bias[cl];
#pragma unroll
      for (int mf = 0; mf < 4; ++mf) {
        int row = m0 + wr + mf * 16 + g * 4;
#pragma unroll
        for (int j = 0; j < 4; ++j)
          outb[outoff + (size_t)(row + j) * 1024 + cl] = f2bf(acc[mf][nf][j] + bv);
      }
    }
  } else {
#pragma unroll
    for (int nf = 0; nf < 4; ++nf) {
      int col = n0 + wc + nf * 16 + qi;
      float bv = bias0[col];
#pragma unroll
      for (int mf = 0; mf < 4; ++mf) {
        int row = m0 + wr + mf * 16 + g * 4;
#pragma unroll
        for (int j = 0; j < 4; ++j)
          outf[(size_t)(row + j) * 1024 + col] = acc[mf][nf][j] + bv;
      }
    }
  }
}

// ---------------- banded flash attention ----------------
// block = (b, h, q-tile of 64). 4 waves x 16 q-rows. Swapped QK^T: ST = mfma(K, Q)
// so q is lane-local (lane&15); PV accumulated as out^T (A = V^T, B = P^T).
__global__ __launch_bounds__(256, 2) void k_attn(const short* __restrict__ qg_,
                                                 const short* __restrict__ kg_,
                                                 const short* __restrict__ vT,
                                                 short* __restrict__ outp) {
  __shared__ short Qs[64 * 72];
  __shared__ short Ks[64 * 72];
  __shared__ short Vs[64 * 72];
  __shared__ short Ps[4][16 * 72];
  int bid = blockIdx.x;
  int qt = bid & 31, h = (bid >> 5) & 15, b = bid >> 9;
  int q0 = qt * 64;
  int tid = threadIdx.x, lane = tid & 63, w = tid >> 6;
  int g = lane >> 4, qi = lane & 15;

  const short* qsrc = qg_ + ((size_t)b * 2048 + q0) * 1024 + h * 64;
#pragma unroll
  for (int i = 0; i < 2; ++i) {
    int idx = tid + i * 256;
    int r = idx >> 3, c = (idx & 7) << 3;
    *(short8*)&Qs[r * 72 + c] = *(const short8*)&qsrc[(size_t)r * 1024 + c];
  }

  float m = -1e30f, l = 0.f;
  f32x4 oacc[4];
#pragma unroll
  for (int i = 0; i < 4; ++i) oacc[i] = (f32x4)(0.0f);
  int qglob = q0 + w * 16 + qi;

  for (int cc = 0; cc < 5; ++cc) {
    int kb0 = q0 - 128 + cc * 64;         // chunk start; fully in or fully out of range
    if (kb0 < 0 || kb0 >= 2048) continue; // uniform over block
    __syncthreads();                      // protects Ks/Vs overwrite + first-iter Qs visibility
    const short* ksrc = kg_ + ((size_t)b * 2048 + kb0) * 1024 + h * 64;
    const short* vsrc = vT + ((size_t)(b * 16 + h)) * 64 * 2048 + kb0;
#pragma unroll
    for (int i = 0; i < 2; ++i) {
      int idx = tid + i * 256;
      int r = idx >> 3, c = (idx & 7) << 3;
      *(short8*)&Ks[r * 72 + c] = *(const short8*)&ksrc[(size_t)r * 1024 + c];
      *(short8*)&Vs[r * 72 + c] = *(const short8*)&vsrc[(size_t)r * 2048 + c];  // Vs[d][k]
    }
    __syncthreads();

    // ST[kcol][q] = sum_d K[kcol][d] * Q[q][d]
    f32x4 st[4];
#pragma unroll
    for (int i = 0; i < 4; ++i) st[i] = (f32x4)(0.0f);
#pragma unroll
    for (int ds = 0; ds < 2; ++ds) {
      bf16x8 qf = *(const bf16x8*)&Qs[(w * 16 + qi) * 72 + ds * 32 + g * 8];
#pragma unroll
      for (int mf = 0; mf < 4; ++mf) {
        bf16x8 kf = *(const bf16x8*)&Ks[(mf * 16 + qi) * 72 + ds * 32 + g * 8];
        st[mf] = __builtin_amdgcn_mfma_f32_16x16x32_bf16(kf, qf, st[mf], 0, 0, 0);
      }
    }

    // mask + online softmax (q = lane&15 is lane-local; rows of ST are k)
    float pv[16];
    float pm = -1e30f;
#pragma unroll
    for (int mf = 0; mf < 4; ++mf)
#pragma unroll
      for (int j = 0; j < 4; ++j) {
        int kcol = kb0 + mf * 16 + g * 4 + j;
        float s = st[mf][j] * 0.125f;     // / sqrt(64)
        int d = kcol - qglob;
        bool valid = (d >= -128) && (d <= 128);
        s = valid ? s : -1e30f;
        pv[mf * 4 + j] = s;
        pm = fmaxf(pm, s);
      }
    pm = fmaxf(pm, __shfl_xor(pm, 16));
    pm = fmaxf(pm, __shfl_xor(pm, 32));
    float mnew = fmaxf(m, pm);
    float scale = __expf(m - mnew);
    float ls = 0.f;
#pragma unroll
    for (int e = 0; e < 16; ++e) {
      float p = pv[e] > -1e29f ? __expf(pv[e] - mnew) : 0.f;
      pv[e] = p;
      ls += p;
    }
    ls += __shfl_xor(ls, 16);
    ls += __shfl_xor(ls, 32);
    l = l * scale + ls;
    m = mnew;
#pragma unroll
    for (int mf = 0; mf < 4; ++mf) oacc[mf] *= scale;

    // write P^T (bf16) to per-wave LDS: Ps[w][q][k], row stride 72
#pragma unroll
    for (int f = 0; f < 4; ++f) {
      short4v pk;
#pragma unroll
      for (int j = 0; j < 4; ++j) pk[j] = f2bf(pv[f * 4 + j]);
      *(short4v*)&Ps[w][qi * 72 + f * 16 + g * 4] = pk;
    }

    // out^T[d][q] += sum_k V^T[d][k] * P^T[k][q]
#pragma unroll
    for (int ks = 0; ks < 2; ++ks) {
      bf16x8 pf = *(const bf16x8*)&Ps[w][qi * 72 + ks * 32 + g * 8];
#pragma unroll
      for (int mf = 0; mf < 4; ++mf) {
        bf16x8 vf = *(const bf16x8*)&Vs[(mf * 16 + qi) * 72 + ks * 32 + g * 8];
        oacc[mf] = __builtin_amdgcn_mfma_f32_16x16x32_bf16(vf, pf, oacc[mf], 0, 0, 0);
      }
    }
  }

  // epilogue: /l, transpose via LDS (reuse Ks), coalesced bf16 store
  __syncthreads();
  short* Os = Ks;
  float inv = 1.f / l;
#pragma unroll
  for (int mf = 0; mf < 4; ++mf) {
    short4v pk;
#pragma unroll
    for (int j = 0; j < 4; ++j) pk[j] = f2bf(oacc[mf][j] * inv);
    *(short4v*)&Os[(w * 16 + qi) * 72 + mf * 16 + g * 4] = pk;
  }
  __syncthreads();
  short* dst = outp + ((size_t)b * 2048 + q0) * 1024 + h * 64;
  int r = tid >> 2, c16 = (tid & 3) << 4;
  *(short8*)&dst[(size_t)r * 1024 + c16] = *(const short8*)&Os[r * 72 + c16];
  *(short8*)&dst[(size_t)r * 1024 + c16 + 8] = *(const short8*)&Os[r * 72 + c16 + 8];
}

extern "C" void kernel_launch(void* const* d_in, const int* in_sizes, int n_in,
                              void* d_out, int out_size, void* d_ws, size_t ws_size,
                              hipStream_t stream) {
  const float* x  = (const float*)d_in[0];
  const float* Wq = (const float*)d_in[1];
  const float* bq = (const float*)d_in[2];
  const float* Wk = (const float*)d_in[3];
  const float* bk = (const float*)d_in[4];
  const float* Wv = (const float*)d_in[5];
  const float* bv = (const float*)d_in[6];
  const float* Wo = (const float*)d_in[7];
  const float* bo = (const float*)d_in[8];

  short* ws = (short*)d_ws;
  // layout (shorts): [0, 4M) xb -> later vT ; [4M, 16M) q,k,v ; v region reused as attn_out
  // [16M, 20M) WqT,WkT,WvT,WoT
  short* xb       = ws;
  short* qkv      = ws + 4194304;
  short* vbuf     = qkv + 2 * 4194304;
  short* vT       = ws;            // aliases xb (dead after QKV GEMM)
  short* attn_out = vbuf;          // aliases vbuf (dead after k_tv)
  short* WT       = ws + 4 * 4194304;

  k_cast_x<<<2048, 256, 0, stream>>>(x, xb);
  k_tw<<<1024, 256, 0, stream>>>(Wq, Wk, Wv, Wo, WT);
  {
    dim3 grid(24, 32);
    k_gemm<0><<<grid, 256, 0, stream>>>(xb, WT, bq, bk, bv, qkv, nullptr);
  }
  k_tv<<<1024, 256, 0, stream>>>(vbuf, vT);
  k_attn<<<1024, 256, 0, stream>>>(qkv, qkv + 4194304, vT, attn_out);
  {
    dim3 grid(8, 32);
    k_gemm<1><<<grid, 256, 0, stream>>>(attn_out, WT + 3 * 1048576, bo, bo, bo, nullptr, (float*)d_out);
  }
}

// Round 2
// 96.339 us; speedup vs baseline: 1.0425x; 1.0425x over previous
//
#include <hip/hip_runtime.h>
#include <cstdint>
#include <cstddef>

typedef __attribute__((ext_vector_type(8))) short short8;
typedef __attribute__((ext_vector_type(4))) short short4v;
typedef __attribute__((ext_vector_type(4))) float f32x4;
typedef short8 bf16x8;

typedef __attribute__((address_space(1))) const unsigned GU;
typedef __attribute__((address_space(3))) unsigned LU;

__device__ __forceinline__ short f2bf(float f) {
  unsigned u = __builtin_bit_cast(unsigned, f);
  u += 0x7fffu + ((u >> 16) & 1u);   // RNE; inputs are finite normals
  return (short)(u >> 16);
}

// ---------------- cast x (f32 -> bf16) ----------------
__global__ __launch_bounds__(256) void k_cast_x(const float* __restrict__ x, short* __restrict__ xb) {
  size_t i = ((size_t)blockIdx.x * 256 + threadIdx.x) * 8;
  f32x4 a = *(const f32x4*)(x + i);
  f32x4 b = *(const f32x4*)(x + i + 4);
  short8 o;
#pragma unroll
  for (int j = 0; j < 4; ++j) { o[j] = f2bf(a[j]); o[4 + j] = f2bf(b[j]); }
  *(short8*)(xb + i) = o;
}

// ---------------- cast + transpose weights: WT[n][k] = W[k][n] (bf16) ----------------
__global__ __launch_bounds__(256) void k_tw(const float* __restrict__ W0, const float* __restrict__ W1,
                                            const float* __restrict__ W2, const float* __restrict__ W3,
                                            short* __restrict__ WT) {
  __shared__ short T[64 * 72];
  int bid = blockIdx.x;
  int widx = bid >> 8;
  int t = bid & 255;
  int kr = (t >> 4) * 64, nc = (t & 15) * 64;
  const float* W = widx == 0 ? W0 : widx == 1 ? W1 : widx == 2 ? W2 : W3;
  short* out = WT + (size_t)widx * 1048576;
  int tid = threadIdx.x;
#pragma unroll
  for (int i = 0; i < 4; ++i) {
    int idx = tid + i * 256;          // 1024 quads of 4 floats
    int k = idx >> 4, n4 = (idx & 15) << 2;
    f32x4 v = *(const f32x4*)(W + (size_t)(kr + k) * 1024 + nc + n4);
#pragma unroll
    for (int j = 0; j < 4; ++j) T[(n4 + j) * 72 + k] = f2bf(v[j]);
  }
  __syncthreads();
#pragma unroll
  for (int i = 0; i < 2; ++i) {
    int idx = tid + i * 256;
    int n = idx >> 3, k8 = (idx & 7) << 3;
    *(short8*)(out + (size_t)(nc + n) * 1024 + kr + k8) = *(const short8*)&T[n * 72 + k8];
  }
}

// ---------------- transpose v: vT[b][h][d][s] = v[b][s][h*64+d] ----------------
__global__ __launch_bounds__(256) void k_tv(const short* __restrict__ v, short* __restrict__ vT) {
  __shared__ short T[64 * 72];
  int bid = blockIdx.x;
  int stile = bid & 31, h = (bid >> 5) & 15, b = bid >> 9;
  int s0 = stile * 64;
  int tid = threadIdx.x;
#pragma unroll
  for (int i = 0; i < 2; ++i) {
    int idx = tid + i * 256;
    int s = idx >> 3, d0 = (idx & 7) << 3;
    short8 vec = *(const short8*)(v + ((size_t)b * 2048 + s0 + s) * 1024 + h * 64 + d0);
#pragma unroll
    for (int j = 0; j < 8; ++j) T[(d0 + j) * 72 + s] = vec[j];
  }
  __syncthreads();
#pragma unroll
  for (int i = 0; i < 2; ++i) {
    int idx = tid + i * 256;
    int d = idx >> 3, s8 = (idx & 7) << 3;
    *(short8*)(vT + (((size_t)b * 16 + h) * 64 + d) * 2048 + s0 + s8) = *(const short8*)&T[d * 72 + s8];
  }
}

// ---------------- GEMM: C[M,N] = A[M,K] * BT[N,K]^T  (bf16 in, fp32 accum) ----------------
// LDS tiles [128][32] linear (global_load_lds). XOR swizzle on 16B chunks:
// LDS chunk cc of row r holds global chunk cc ^ ((r>>1)&3); reader XORs the same.
// MODE 0: bf16 out into qkv buffers (N=3072, bias select per 1024-col group)
// MODE 1: fp32 out (+bias0) into d_out (N=1024)
template <int MODE>
__global__ __launch_bounds__(256, 2) void k_gemm(
    const short* __restrict__ A, const short* __restrict__ BT,
    const float* __restrict__ bias0, const float* __restrict__ bias1, const float* __restrict__ bias2,
    short* __restrict__ outb, float* __restrict__ outf) {
  __shared__ short Smem[16384];   // As[2] @ 0,4096 ; Bs[2] @ 8192,12288 ; epilogue reuse
  const int tid = threadIdx.x;
  const int lane = tid & 63, w = tid >> 6;
  const int g = lane >> 4, qi = lane & 15;
  const int wr = (w >> 1) * 64, wc = (w & 1) * 64;
  const int m0 = blockIdx.y * 128, n0 = blockIdx.x * 128;
  const size_t K = 1024;
  const short* Ab = A + (size_t)m0 * K;
  const short* Bb = BT + (size_t)n0 * K;

  auto stage = [&](int buf, int k0) {
    short* Asb = Smem + buf * 4096;
    short* Bsb = Smem + 8192 + buf * 4096;
#pragma unroll
    for (int i = 0; i < 2; ++i) {
      int cidx = tid + i * 256;               // 512 chunks of 8 bf16 per tile
      int r = cidx >> 2;
      int csw = ((cidx & 3) ^ ((r >> 1) & 3)) << 3;   // pre-swizzled global chunk
      __builtin_amdgcn_global_load_lds((GU*)(Ab + (size_t)r * K + k0 + csw),
                                       (LU*)(&Asb[cidx * 8]), 16, 0, 0);
      __builtin_amdgcn_global_load_lds((GU*)(Bb + (size_t)r * K + k0 + csw),
                                       (LU*)(&Bsb[cidx * 8]), 16, 0, 0);
    }
  };

  f32x4 acc[4][4];
#pragma unroll
  for (int i = 0; i < 4; ++i)
#pragma unroll
    for (int j = 0; j < 4; ++j) acc[i][j] = (f32x4)(0.0f);

  stage(0, 0);
  __syncthreads();
  for (int kt = 0; kt < 32; ++kt) {
    int cur = kt & 1;
    if (kt < 31) stage(cur ^ 1, (kt + 1) * 32);
    const short* Asb = Smem + cur * 4096;
    const short* Bsb = Smem + 8192 + cur * 4096;
    bf16x8 a[4], b[4];
#pragma unroll
    for (int mf = 0; mf < 4; ++mf) {
      int R = wr + mf * 16 + qi;
      a[mf] = *(const bf16x8*)&Asb[R * 32 + ((g ^ ((R >> 1) & 3)) << 3)];
    }
#pragma unroll
    for (int nf = 0; nf < 4; ++nf) {
      int R = wc + nf * 16 + qi;
      b[nf] = *(const bf16x8*)&Bsb[R * 32 + ((g ^ ((R >> 1) & 3)) << 3)];
    }
#pragma unroll
    for (int mf = 0; mf < 4; ++mf)
#pragma unroll
      for (int nf = 0; nf < 4; ++nf)
        acc[mf][nf] = __builtin_amdgcn_mfma_f32_16x16x32_bf16(a[mf], b[nf], acc[mf][nf], 0, 0, 0);
    __syncthreads();
  }

  // -------- coalesced epilogue via LDS transpose (stride 136 shorts/floats, 16B-aligned) --------
  if (MODE == 0) {
    int sel = n0 >> 10;
    const float* bias = sel == 0 ? bias0 : (sel == 1 ? bias1 : bias2);
    size_t outoff = (size_t)sel * 4194304;
    int ncol0 = n0 & 1023;
    float bv[4];
#pragma unroll
    for (int nf = 0; nf < 4; ++nf) bv[nf] = bias[ncol0 + wc + nf * 16 + qi];
    short* Os = Smem;                          // [32][136]
#pragma unroll
    for (int mf = 0; mf < 4; ++mf) {
      __syncthreads();
#pragma unroll
      for (int nf = 0; nf < 4; ++nf)
#pragma unroll
        for (int j = 0; j < 4; ++j)
          Os[((w >> 1) * 16 + g * 4 + j) * 136 + wc + nf * 16 + qi] = f2bf(acc[mf][nf][j] + bv[nf]);
      __syncthreads();
#pragma unroll
      for (int i = 0; i < 2; ++i) {
        int idx = tid + i * 256;
        int r = idx >> 4, c8 = (idx & 15) << 3;
        int row = m0 + ((r >> 4) << 6) + mf * 16 + (r & 15);
        *(short8*)&outb[outoff + (size_t)row * 1024 + ncol0 + c8] = *(const short8*)&Os[r * 136 + c8];
      }
    }
  } else {
    float* Ft = (float*)Smem;                  // [32][136]
    float bv[4];
#pragma unroll
    for (int nf = 0; nf < 4; ++nf) bv[nf] = bias0[n0 + wc + nf * 16 + qi];
#pragma unroll
    for (int mf = 0; mf < 4; ++mf) {
      __syncthreads();
#pragma unroll
      for (int nf = 0; nf < 4; ++nf)
#pragma unroll
        for (int j = 0; j < 4; ++j)
          Ft[((w >> 1) * 16 + g * 4 + j) * 136 + wc + nf * 16 + qi] = acc[mf][nf][j] + bv[nf];
      __syncthreads();
#pragma unroll
      for (int i = 0; i < 4; ++i) {
        int idx = tid + i * 256;
        int r = idx >> 5, c4 = (idx & 31) << 2;
        int row = m0 + ((r >> 4) << 6) + mf * 16 + (r & 15);
        *(f32x4*)&outf[(size_t)row * 1024 + n0 + c4] = *(const f32x4*)&Ft[r * 136 + c4];
      }
    }
  }
}

// ---------------- banded flash attention ----------------
// block = (b, h, q-tile of 64). 4 waves x 16 q-rows. Swapped QK^T: ST = mfma(K, Q)
// so q is lane-local (lane&15); PV accumulated as out^T (A = V^T, B = P^T).
__global__ __launch_bounds__(256, 2) void k_attn(const short* __restrict__ qg_,
                                                 const short* __restrict__ kg_,
                                                 const short* __restrict__ vT,
                                                 short* __restrict__ outp) {
  __shared__ short Qs[64 * 72];
  __shared__ short Ks[64 * 72];
  __shared__ short Vs[64 * 72];
  __shared__ short Ps[4][16 * 72];
  int bid = blockIdx.x;
  int qt = bid & 31, h = (bid >> 5) & 15, b = bid >> 9;
  int q0 = qt * 64;
  int tid = threadIdx.x, lane = tid & 63, w = tid >> 6;
  int g = lane >> 4, qi = lane & 15;

  const short* qsrc = qg_ + ((size_t)b * 2048 + q0) * 1024 + h * 64;
#pragma unroll
  for (int i = 0; i < 2; ++i) {
    int idx = tid + i * 256;
    int r = idx >> 3, c = (idx & 7) << 3;
    *(short8*)&Qs[r * 72 + c] = *(const short8*)&qsrc[(size_t)r * 1024 + c];
  }

  float m = -1e30f, l = 0.f;
  f32x4 oacc[4];
#pragma unroll
  for (int i = 0; i < 4; ++i) oacc[i] = (f32x4)(0.0f);
  int qglob = q0 + w * 16 + qi;

  for (int cc = 0; cc < 5; ++cc) {
    int kb0 = q0 - 128 + cc * 64;         // chunk start; fully in or fully out of range
    if (kb0 < 0 || kb0 >= 2048) continue; // uniform over block
    __syncthreads();                      // protects Ks/Vs overwrite + first-iter Qs visibility
    const short* ksrc = kg_ + ((size_t)b * 2048 + kb0) * 1024 + h * 64;
    const short* vsrc = vT + ((size_t)(b * 16 + h)) * 64 * 2048 + kb0;
#pragma unroll
    for (int i = 0; i < 2; ++i) {
      int idx = tid + i * 256;
      int r = idx >> 3, c = (idx & 7) << 3;
      *(short8*)&Ks[r * 72 + c] = *(const short8*)&ksrc[(size_t)r * 1024 + c];
      *(short8*)&Vs[r * 72 + c] = *(const short8*)&vsrc[(size_t)r * 2048 + c];  // Vs[d][k]
    }
    __syncthreads();

    // ST[kcol][q] = sum_d K[kcol][d] * Q[q][d]
    f32x4 st[4];
#pragma unroll
    for (int i = 0; i < 4; ++i) st[i] = (f32x4)(0.0f);
#pragma unroll
    for (int ds = 0; ds < 2; ++ds) {
      bf16x8 qf = *(const bf16x8*)&Qs[(w * 16 + qi) * 72 + ds * 32 + g * 8];
#pragma unroll
      for (int mf = 0; mf < 4; ++mf) {
        bf16x8 kf = *(const bf16x8*)&Ks[(mf * 16 + qi) * 72 + ds * 32 + g * 8];
        st[mf] = __builtin_amdgcn_mfma_f32_16x16x32_bf16(kf, qf, st[mf], 0, 0, 0);
      }
    }

    // mask + online softmax (q = lane&15 is lane-local; rows of ST are k)
    float pv[16];
    float pm = -1e30f;
#pragma unroll
    for (int mf = 0; mf < 4; ++mf)
#pragma unroll
      for (int j = 0; j < 4; ++j) {
        int kcol = kb0 + mf * 16 + g * 4 + j;
        float s = st[mf][j] * 0.125f;     // / sqrt(64)
        int d = kcol - qglob;
        bool valid = (d >= -128) && (d <= 128);
        s = valid ? s : -1e30f;
        pv[mf * 4 + j] = s;
        pm = fmaxf(pm, s);
      }
    pm = fmaxf(pm, __shfl_xor(pm, 16));
    pm = fmaxf(pm, __shfl_xor(pm, 32));
    float mnew = fmaxf(m, pm);
    float scale = __expf(m - mnew);
    float ls = 0.f;
#pragma unroll
    for (int e = 0; e < 16; ++e) {
      float p = pv[e] > -1e29f ? __expf(pv[e] - mnew) : 0.f;
      pv[e] = p;
      ls += p;
    }
    ls += __shfl_xor(ls, 16);
    ls += __shfl_xor(ls, 32);
    l = l * scale + ls;
    m = mnew;
#pragma unroll
    for (int mf = 0; mf < 4; ++mf) oacc[mf] *= scale;

    // write P^T (bf16) to per-wave LDS: Ps[w][q][k], row stride 72
#pragma unroll
    for (int f = 0; f < 4; ++f) {
      short4v pk;
#pragma unroll
      for (int j = 0; j < 4; ++j) pk[j] = f2bf(pv[f * 4 + j]);
      *(short4v*)&Ps[w][qi * 72 + f * 16 + g * 4] = pk;
    }

    // out^T[d][q] += sum_k V^T[d][k] * P^T[k][q]
#pragma unroll
    for (int ks = 0; ks < 2; ++ks) {
      bf16x8 pf = *(const bf16x8*)&Ps[w][qi * 72 + ks * 32 + g * 8];
#pragma unroll
      for (int mf = 0; mf < 4; ++mf) {
        bf16x8 vf = *(const bf16x8*)&Vs[(mf * 16 + qi) * 72 + ks * 32 + g * 8];
        oacc[mf] = __builtin_amdgcn_mfma_f32_16x16x32_bf16(vf, pf, oacc[mf], 0, 0, 0);
      }
    }
  }

  // epilogue: /l, transpose via LDS (reuse Ks), coalesced bf16 store
  __syncthreads();
  short* Os = Ks;
  float inv = 1.f / l;
#pragma unroll
  for (int mf = 0; mf < 4; ++mf) {
    short4v pk;
#pragma unroll
    for (int j = 0; j < 4; ++j) pk[j] = f2bf(oacc[mf][j] * inv);
    *(short4v*)&Os[(w * 16 + qi) * 72 + mf * 16 + g * 4] = pk;
  }
  __syncthreads();
  short* dst = outp + ((size_t)b * 2048 + q0) * 1024 + h * 64;
  int r = tid >> 2, c16 = (tid & 3) << 4;
  *(short8*)&dst[(size_t)r * 1024 + c16] = *(const short8*)&Os[r * 72 + c16];
  *(short8*)&dst[(size_t)r * 1024 + c16 + 8] = *(const short8*)&Os[r * 72 + c16 + 8];
}

extern "C" void kernel_launch(void* const* d_in, const int* in_sizes, int n_in,
                              void* d_out, int out_size, void* d_ws, size_t ws_size,
                              hipStream_t stream) {
  const float* x  = (const float*)d_in[0];
  const float* Wq = (const float*)d_in[1];
  const float* bq = (const float*)d_in[2];
  const float* Wk = (const float*)d_in[3];
  const float* bk = (const float*)d_in[4];
  const float* Wv = (const float*)d_in[5];
  const float* bv = (const float*)d_in[6];
  const float* Wo = (const float*)d_in[7];
  const float* bo = (const float*)d_in[8];

  short* ws = (short*)d_ws;
  // layout (shorts): [0, 4M) xb -> later vT ; [4M, 16M) q,k,v ; v region reused as attn_out
  // [16M, 20M) WqT,WkT,WvT,WoT
  short* xb       = ws;
  short* qkv      = ws + 4194304;
  short* vbuf     = qkv + 2 * 4194304;
  short* vT       = ws;            // aliases xb (dead after QKV GEMM)
  short* attn_out = vbuf;          // aliases vbuf (dead after k_tv)
  short* WT       = ws + 4 * 4194304;

  k_cast_x<<<2048, 256, 0, stream>>>(x, xb);
  k_tw<<<1024, 256, 0, stream>>>(Wq, Wk, Wv, Wo, WT);
  {
    dim3 grid(24, 32);
    k_gemm<0><<<grid, 256, 0, stream>>>(xb, WT, bq, bk, bv, qkv, nullptr);
  }
  k_tv<<<1024, 256, 0, stream>>>(vbuf, vT);
  k_attn<<<1024, 256, 0, stream>>>(qkv, qkv + 4194304, vT, attn_out);
  {
    dim3 grid(8, 32);
    k_gemm<1><<<grid, 256, 0, stream>>>(attn_out, WT + 3 * 1048576, bo, bo, bo, nullptr, (float*)d_out);
  }
}

// Round 3
// 92.980 us; speedup vs baseline: 1.0801x; 1.0361x over previous
//
#include <hip/hip_runtime.h>
#include <cstdint>
#include <cstddef>

typedef __attribute__((ext_vector_type(8))) short short8;
typedef __attribute__((ext_vector_type(4))) short short4v;
typedef __attribute__((ext_vector_type(4))) float f32x4;
typedef short8 bf16x8;

typedef __attribute__((address_space(1))) const unsigned GU;
typedef __attribute__((address_space(3))) unsigned LU;

__device__ __forceinline__ short f2bf(float f) {
  unsigned u = __builtin_bit_cast(unsigned, f);
  u += 0x7fffu + ((u >> 16) & 1u);   // RNE; inputs are finite normals
  return (short)(u >> 16);
}

// ---------------- cast x (f32 -> bf16) ----------------
__global__ __launch_bounds__(256) void k_cast_x(const float* __restrict__ x, short* __restrict__ xb) {
  size_t i = ((size_t)blockIdx.x * 256 + threadIdx.x) * 8;
  f32x4 a = *(const f32x4*)(x + i);
  f32x4 b = *(const f32x4*)(x + i + 4);
  short8 o;
#pragma unroll
  for (int j = 0; j < 4; ++j) { o[j] = f2bf(a[j]); o[4 + j] = f2bf(b[j]); }
  *(short8*)(xb + i) = o;
}

// ---------------- cast + transpose weights: WT[n][k] = W[k][n] (bf16) ----------------
__global__ __launch_bounds__(256) void k_tw(const float* __restrict__ W0, const float* __restrict__ W1,
                                            const float* __restrict__ W2, const float* __restrict__ W3,
                                            short* __restrict__ WT) {
  __shared__ short T[64 * 72];
  int bid = blockIdx.x;
  int widx = bid >> 8;
  int t = bid & 255;
  int kr = (t >> 4) * 64, nc = (t & 15) * 64;
  const float* W = widx == 0 ? W0 : widx == 1 ? W1 : widx == 2 ? W2 : W3;
  short* out = WT + (size_t)widx * 1048576;
  int tid = threadIdx.x;
#pragma unroll
  for (int i = 0; i < 4; ++i) {
    int idx = tid + i * 256;          // 1024 quads of 4 floats
    int k = idx >> 4, n4 = (idx & 15) << 2;
    f32x4 v = *(const f32x4*)(W + (size_t)(kr + k) * 1024 + nc + n4);
#pragma unroll
    for (int j = 0; j < 4; ++j) T[(n4 + j) * 72 + k] = f2bf(v[j]);
  }
  __syncthreads();
#pragma unroll
  for (int i = 0; i < 2; ++i) {
    int idx = tid + i * 256;
    int n = idx >> 3, k8 = (idx & 7) << 3;
    *(short8*)(out + (size_t)(nc + n) * 1024 + kr + k8) = *(const short8*)&T[n * 72 + k8];
  }
}

// ---------------- transpose v: vT[b][h][d][s] = v[b][s][h*64+d] ----------------
__global__ __launch_bounds__(256) void k_tv(const short* __restrict__ v, short* __restrict__ vT) {
  __shared__ short T[64 * 72];
  int bid = blockIdx.x;
  int stile = bid & 31, h = (bid >> 5) & 15, b = bid >> 9;
  int s0 = stile * 64;
  int tid = threadIdx.x;
#pragma unroll
  for (int i = 0; i < 2; ++i) {
    int idx = tid + i * 256;
    int s = idx >> 3, d0 = (idx & 7) << 3;
    short8 vec = *(const short8*)(v + ((size_t)b * 2048 + s0 + s) * 1024 + h * 64 + d0);
#pragma unroll
    for (int j = 0; j < 8; ++j) T[(d0 + j) * 72 + s] = vec[j];
  }
  __syncthreads();
#pragma unroll
  for (int i = 0; i < 2; ++i) {
    int idx = tid + i * 256;
    int d = idx >> 3, s8 = (idx & 7) << 3;
    *(short8*)(vT + (((size_t)b * 16 + h) * 64 + d) * 2048 + s0 + s8) = *(const short8*)&T[d * 72 + s8];
  }
}

// ================= 256x256 8-phase QKV GEMM (T1+T2+T3+T4+T5) =================
// C[4096,3072] = A[4096,1024] * BT[3072,1024]^T, bf16 in, fp32 acc, bf16 out (+bias).
// 512 thr = 8 waves (2M x 4N); per-wave out 128x64. BK=64 as two 32-wide k-halves.
// LDS 128KB: region(buf,ab,kh) = buf*32768 + ab*16384 + kh*8192 shorts, each [256][32].
// Phase = {8 ds_read_b128, stage 1 region (2 gll x16B), barrier, lgkmcnt(0), 16 MFMA, barrier}.
// Region schedule (iter j computes tiles 2j->bufA, 2j+1->bufB):
//  ph0 (A,kh0,rh0) stage bufB.Akh1<-2j+1 | ph1 (A,kh0,rh1) stage bufB.Bkh1<-2j+1
//  ph2 (A,kh1,rh0) stage bufA.Akh0<-2j+2 | ph3 (A,kh1,rh1) stage bufA.Bkh0<-2j+2, vmcnt(4)
//  ph4 (B,kh0,rh0) stage bufA.Akh1<-2j+2 | ph5 (B,kh0,rh1) stage bufA.Bkh1<-2j+2
//  ph6 (B,kh1,rh0) stage bufB.Akh0<-2j+3 | ph7 (B,kh1,rh1) stage bufB.Bkh0<-2j+3, vmcnt(4)
// Each staged region is dead (fully read, barrier-separated) at issue; vmcnt(4) at
// ph3/ph7 guarantees the next tile landed with exactly 2 regions still in flight.
// Last iter clamps stage tiles to 15 (dead-region rewrites) to keep vmcnt counts exact.
__global__ __launch_bounds__(512, 2) void k_gemm256(
    const short* __restrict__ A, const short* __restrict__ BT,
    const float* __restrict__ bias0, const float* __restrict__ bias1, const float* __restrict__ bias2,
    short* __restrict__ outb) {
  __shared__ short S[65536];
  const int tid = threadIdx.x;
  const int lane = tid & 63, w = tid >> 6;
  const int g = lane >> 4, qi = lane & 15;
  const int wm = w >> 2, wn = w & 3;
  int bid = blockIdx.x;
  int swz = (bid & 7) * 24 + (bid >> 3);      // 192 = 8 XCD x 24, bijective
  const int tm = swz / 12, tn = swz % 12;
  const int m0 = tm * 256, n0 = tn * 256;
  const size_t K = 1024;
  const short* Ab = A + (size_t)m0 * K;
  const short* Bb = BT + (size_t)n0 * K;

  auto stage = [&](int roff, const short* gbase, int kt, int kh) {
    int k0 = kt * 64 + kh * 32;
#pragma unroll
    for (int i = 0; i < 2; ++i) {
      int c = tid + i * 512;
      int r = c >> 2;
      int csw = ((c & 3) ^ ((r >> 1) & 3)) << 3;   // pre-swizzled global chunk
      __builtin_amdgcn_global_load_lds((GU*)(gbase + (size_t)r * K + k0 + csw),
                                       (LU*)(&S[roff + c * 8]), 16, 0, 0);
    }
  };
  auto lda = [&](int roff, int row) -> bf16x8 {
    return *(const bf16x8*)&S[roff + row * 32 + ((g ^ ((row >> 1) & 3)) << 3)];
  };

  f32x4 acc[8][4];
#pragma unroll
  for (int i = 0; i < 8; ++i)
#pragma unroll
    for (int j = 0; j < 4; ++j) acc[i][j] = (f32x4)(0.0f);

#define MF1(rh, mf, nf, av, bv) \
  acc[(rh)*4+(mf)][(nf)] = __builtin_amdgcn_mfma_f32_16x16x32_bf16(av, bv, acc[(rh)*4+(mf)][(nf)], 0, 0, 0)

#define GPH(buf, kh, rh, ...) do { \
    const int ra_ = (buf)*32768 + (kh)*8192; \
    const int rb_ = (buf)*32768 + 16384 + (kh)*8192; \
    const int ar_ = wm*128 + (rh)*64 + qi; \
    bf16x8 a0 = lda(ra_, ar_ + 0);  bf16x8 a1 = lda(ra_, ar_ + 16); \
    bf16x8 a2 = lda(ra_, ar_ + 32); bf16x8 a3 = lda(ra_, ar_ + 48); \
    const int br_ = wn*64 + qi; \
    bf16x8 b0 = lda(rb_, br_ + 0);  bf16x8 b1 = lda(rb_, br_ + 16); \
    bf16x8 b2 = lda(rb_, br_ + 32); bf16x8 b3 = lda(rb_, br_ + 48); \
    __VA_ARGS__; \
    __builtin_amdgcn_sched_barrier(0); \
    __builtin_amdgcn_s_barrier(); \
    asm volatile("s_waitcnt lgkmcnt(0)" ::: "memory"); \
    __builtin_amdgcn_sched_barrier(0); \
    __builtin_amdgcn_s_setprio(1); \
    MF1(rh,0,0,a0,b0); MF1(rh,0,1,a0,b1); MF1(rh,0,2,a0,b2); MF1(rh,0,3,a0,b3); \
    MF1(rh,1,0,a1,b0); MF1(rh,1,1,a1,b1); MF1(rh,1,2,a1,b2); MF1(rh,1,3,a1,b3); \
    MF1(rh,2,0,a2,b0); MF1(rh,2,1,a2,b1); MF1(rh,2,2,a2,b2); MF1(rh,2,3,a2,b3); \
    MF1(rh,3,0,a3,b0); MF1(rh,3,1,a3,b1); MF1(rh,3,2,a3,b2); MF1(rh,3,3,a3,b3); \
    __builtin_amdgcn_s_setprio(0); \
    __builtin_amdgcn_sched_barrier(0); \
  } while (0)

  // prologue: tile0 (4 regions) + tile1 kh0 (2 regions) = 12 loads/thread
  stage(0,     Ab, 0, 0);
  stage(16384, Bb, 0, 0);
  stage(8192,  Ab, 0, 1);
  stage(24576, Bb, 0, 1);
  stage(32768, Ab, 1, 0);
  stage(49152, Bb, 1, 0);
  asm volatile("s_waitcnt vmcnt(4)" ::: "memory");   // tile0 landed
  __builtin_amdgcn_s_barrier();

  for (int j = 0; j < 8; ++j) {
    int t1 = 2 * j + 1;
    int t2 = 2 * j + 2; t2 = t2 < 15 ? t2 : 15;      // clamp: dead-region rewrite on last iter
    int t3 = 2 * j + 3; t3 = t3 < 15 ? t3 : 15;
    GPH(0, 0, 0, stage(40960, Ab, t1, 1));  __builtin_amdgcn_s_barrier();
    GPH(0, 0, 1, stage(57344, Bb, t1, 1));  __builtin_amdgcn_s_barrier();
    GPH(0, 1, 0, stage(0,     Ab, t2, 0));  __builtin_amdgcn_s_barrier();
    GPH(0, 1, 1, stage(16384, Bb, t2, 0));
      asm volatile("s_waitcnt vmcnt(4)" ::: "memory");  // tile 2j+1 fully landed
      __builtin_amdgcn_s_barrier();
    GPH(1, 0, 0, stage(8192,  Ab, t2, 1));  __builtin_amdgcn_s_barrier();
    GPH(1, 0, 1, stage(24576, Bb, t2, 1));  __builtin_amdgcn_s_barrier();
    GPH(1, 1, 0, stage(32768, Ab, t3, 0));  __builtin_amdgcn_s_barrier();
    GPH(1, 1, 1, stage(49152, Bb, t3, 0));
      asm volatile("s_waitcnt vmcnt(4)" ::: "memory");  // tile 2j+2 fully landed
      __builtin_amdgcn_s_barrier();
  }
#undef GPH
#undef MF1

  // epilogue: drain dead stages, then LDS-transpose coalesced bf16 stores
  asm volatile("s_waitcnt vmcnt(0)" ::: "memory");
  __syncthreads();
  int sel = n0 >> 10;
  const float* bias = sel == 0 ? bias0 : (sel == 1 ? bias1 : bias2);
  size_t outoff = (size_t)sel * 4194304;
  int ncol0 = n0 & 1023;
  float bv[4];
#pragma unroll
  for (int nf = 0; nf < 4; ++nf) bv[nf] = bias[ncol0 + wn * 64 + nf * 16 + qi];
  short* Ep = S;                                   // [128][264]
#pragma unroll
  for (int rh = 0; rh < 2; ++rh) {
    __syncthreads();
#pragma unroll
    for (int mf = 0; mf < 4; ++mf)
#pragma unroll
      for (int nf = 0; nf < 4; ++nf)
#pragma unroll
        for (int j = 0; j < 4; ++j)
          Ep[(wm * 64 + mf * 16 + g * 4 + j) * 264 + wn * 64 + nf * 16 + qi] =
              f2bf(acc[rh * 4 + mf][nf][j] + bv[nf]);
    __syncthreads();
#pragma unroll
    for (int i = 0; i < 8; ++i) {
      int idx = tid + i * 512;                     // 4096 chunks of 8 bf16
      int r = idx >> 5, c8 = (idx & 31) << 3;
      int grow = m0 + (r >> 6) * 128 + rh * 64 + (r & 63);
      *(short8*)&outb[outoff + (size_t)grow * 1024 + ncol0 + c8] = *(const short8*)&Ep[r * 264 + c8];
    }
  }
}

// ---------------- final GEMM (128^2, MODE-1 only): out = attn_out * WoT^T + bo ----------------
__global__ __launch_bounds__(256, 2) void k_gemmO(
    const short* __restrict__ A, const short* __restrict__ BT,
    const float* __restrict__ bias0, float* __restrict__ outf) {
  __shared__ short Smem[16384];
  const int tid = threadIdx.x;
  const int lane = tid & 63, w = tid >> 6;
  const int g = lane >> 4, qi = lane & 15;
  const int wr = (w >> 1) * 64, wc = (w & 1) * 64;
  const int m0 = blockIdx.y * 128, n0 = blockIdx.x * 128;
  const size_t K = 1024;
  const short* Ab = A + (size_t)m0 * K;
  const short* Bb = BT + (size_t)n0 * K;

  auto stage = [&](int buf, int k0) {
    short* Asb = Smem + buf * 4096;
    short* Bsb = Smem + 8192 + buf * 4096;
#pragma unroll
    for (int i = 0; i < 2; ++i) {
      int cidx = tid + i * 256;
      int r = cidx >> 2;
      int csw = ((cidx & 3) ^ ((r >> 1) & 3)) << 3;
      __builtin_amdgcn_global_load_lds((GU*)(Ab + (size_t)r * K + k0 + csw),
                                       (LU*)(&Asb[cidx * 8]), 16, 0, 0);
      __builtin_amdgcn_global_load_lds((GU*)(Bb + (size_t)r * K + k0 + csw),
                                       (LU*)(&Bsb[cidx * 8]), 16, 0, 0);
    }
  };

  f32x4 acc[4][4];
#pragma unroll
  for (int i = 0; i < 4; ++i)
#pragma unroll
    for (int j = 0; j < 4; ++j) acc[i][j] = (f32x4)(0.0f);

  stage(0, 0);
  __syncthreads();
  for (int kt = 0; kt < 32; ++kt) {
    int cur = kt & 1;
    if (kt < 31) stage(cur ^ 1, (kt + 1) * 32);
    const short* Asb = Smem + cur * 4096;
    const short* Bsb = Smem + 8192 + cur * 4096;
    bf16x8 a[4], b[4];
#pragma unroll
    for (int mf = 0; mf < 4; ++mf) {
      int R = wr + mf * 16 + qi;
      a[mf] = *(const bf16x8*)&Asb[R * 32 + ((g ^ ((R >> 1) & 3)) << 3)];
    }
#pragma unroll
    for (int nf = 0; nf < 4; ++nf) {
      int R = wc + nf * 16 + qi;
      b[nf] = *(const bf16x8*)&Bsb[R * 32 + ((g ^ ((R >> 1) & 3)) << 3)];
    }
#pragma unroll
    for (int mf = 0; mf < 4; ++mf)
#pragma unroll
      for (int nf = 0; nf < 4; ++nf)
        acc[mf][nf] = __builtin_amdgcn_mfma_f32_16x16x32_bf16(a[mf], b[nf], acc[mf][nf], 0, 0, 0);
    __syncthreads();
  }

  float* Ft = (float*)Smem;                  // [32][136]
  float bv[4];
#pragma unroll
  for (int nf = 0; nf < 4; ++nf) bv[nf] = bias0[n0 + wc + nf * 16 + qi];
#pragma unroll
  for (int mf = 0; mf < 4; ++mf) {
    __syncthreads();
#pragma unroll
    for (int nf = 0; nf < 4; ++nf)
#pragma unroll
      for (int j = 0; j < 4; ++j)
        Ft[((w >> 1) * 16 + g * 4 + j) * 136 + wc + nf * 16 + qi] = acc[mf][nf][j] + bv[nf];
    __syncthreads();
#pragma unroll
    for (int i = 0; i < 4; ++i) {
      int idx = tid + i * 256;
      int r = idx >> 5, c4 = (idx & 31) << 2;
      int row = m0 + ((r >> 4) << 6) + mf * 16 + (r & 15);
      *(f32x4*)&outf[(size_t)row * 1024 + n0 + c4] = *(const f32x4*)&Ft[r * 136 + c4];
    }
  }
}

// ---------------- banded flash attention ----------------
__global__ __launch_bounds__(256, 2) void k_attn(const short* __restrict__ qg_,
                                                 const short* __restrict__ kg_,
                                                 const short* __restrict__ vT,
                                                 short* __restrict__ outp) {
  __shared__ short Qs[64 * 72];
  __shared__ short Ks[64 * 72];
  __shared__ short Vs[64 * 72];
  __shared__ short Ps[4][16 * 72];
  int bid = blockIdx.x;
  int qt = bid & 31, h = (bid >> 5) & 15, b = bid >> 9;
  int q0 = qt * 64;
  int tid = threadIdx.x, lane = tid & 63, w = tid >> 6;
  int g = lane >> 4, qi = lane & 15;

  const short* qsrc = qg_ + ((size_t)b * 2048 + q0) * 1024 + h * 64;
#pragma unroll
  for (int i = 0; i < 2; ++i) {
    int idx = tid + i * 256;
    int r = idx >> 3, c = (idx & 7) << 3;
    *(short8*)&Qs[r * 72 + c] = *(const short8*)&qsrc[(size_t)r * 1024 + c];
  }

  float m = -1e30f, l = 0.f;
  f32x4 oacc[4];
#pragma unroll
  for (int i = 0; i < 4; ++i) oacc[i] = (f32x4)(0.0f);
  int qglob = q0 + w * 16 + qi;

  for (int cc = 0; cc < 5; ++cc) {
    int kb0 = q0 - 128 + cc * 64;
    if (kb0 < 0 || kb0 >= 2048) continue;
    __syncthreads();
    const short* ksrc = kg_ + ((size_t)b * 2048 + kb0) * 1024 + h * 64;
    const short* vsrc = vT + ((size_t)(b * 16 + h)) * 64 * 2048 + kb0;
#pragma unroll
    for (int i = 0; i < 2; ++i) {
      int idx = tid + i * 256;
      int r = idx >> 3, c = (idx & 7) << 3;
      *(short8*)&Ks[r * 72 + c] = *(const short8*)&ksrc[(size_t)r * 1024 + c];
      *(short8*)&Vs[r * 72 + c] = *(const short8*)&vsrc[(size_t)r * 2048 + c];
    }
    __syncthreads();

    f32x4 st[4];
#pragma unroll
    for (int i = 0; i < 4; ++i) st[i] = (f32x4)(0.0f);
#pragma unroll
    for (int ds = 0; ds < 2; ++ds) {
      bf16x8 qf = *(const bf16x8*)&Qs[(w * 16 + qi) * 72 + ds * 32 + g * 8];
#pragma unroll
      for (int mf = 0; mf < 4; ++mf) {
        bf16x8 kf = *(const bf16x8*)&Ks[(mf * 16 + qi) * 72 + ds * 32 + g * 8];
        st[mf] = __builtin_amdgcn_mfma_f32_16x16x32_bf16(kf, qf, st[mf], 0, 0, 0);
      }
    }

    float pv[16];
    float pm = -1e30f;
#pragma unroll
    for (int mf = 0; mf < 4; ++mf)
#pragma unroll
      for (int j = 0; j < 4; ++j) {
        int kcol = kb0 + mf * 16 + g * 4 + j;
        float s = st[mf][j] * 0.125f;
        int d = kcol - qglob;
        bool valid = (d >= -128) && (d <= 128);
        s = valid ? s : -1e30f;
        pv[mf * 4 + j] = s;
        pm = fmaxf(pm, s);
      }
    pm = fmaxf(pm, __shfl_xor(pm, 16));
    pm = fmaxf(pm, __shfl_xor(pm, 32));
    float mnew = fmaxf(m, pm);
    float scale = __expf(m - mnew);
    float ls = 0.f;
#pragma unroll
    for (int e = 0; e < 16; ++e) {
      float p = pv[e] > -1e29f ? __expf(pv[e] - mnew) : 0.f;
      pv[e] = p;
      ls += p;
    }
    ls += __shfl_xor(ls, 16);
    ls += __shfl_xor(ls, 32);
    l = l * scale + ls;
    m = mnew;
#pragma unroll
    for (int mf = 0; mf < 4; ++mf) oacc[mf] *= scale;

#pragma unroll
    for (int f = 0; f < 4; ++f) {
      short4v pk;
#pragma unroll
      for (int j = 0; j < 4; ++j) pk[j] = f2bf(pv[f * 4 + j]);
      *(short4v*)&Ps[w][qi * 72 + f * 16 + g * 4] = pk;
    }

#pragma unroll
    for (int ks = 0; ks < 2; ++ks) {
      bf16x8 pf = *(const bf16x8*)&Ps[w][qi * 72 + ks * 32 + g * 8];
#pragma unroll
      for (int mf = 0; mf < 4; ++mf) {
        bf16x8 vf = *(const bf16x8*)&Vs[(mf * 16 + qi) * 72 + ks * 32 + g * 8];
        oacc[mf] = __builtin_amdgcn_mfma_f32_16x16x32_bf16(vf, pf, oacc[mf], 0, 0, 0);
      }
    }
  }

  __syncthreads();
  short* Os = Ks;
  float inv = 1.f / l;
#pragma unroll
  for (int mf = 0; mf < 4; ++mf) {
    short4v pk;
#pragma unroll
    for (int j = 0; j < 4; ++j) pk[j] = f2bf(oacc[mf][j] * inv);
    *(short4v*)&Os[(w * 16 + qi) * 72 + mf * 16 + g * 4] = pk;
  }
  __syncthreads();
  short* dst = outp + ((size_t)b * 2048 + q0) * 1024 + h * 64;
  int r = tid >> 2, c16 = (tid & 3) << 4;
  *(short8*)&dst[(size_t)r * 1024 + c16] = *(const short8*)&Os[r * 72 + c16];
  *(short8*)&dst[(size_t)r * 1024 + c16 + 8] = *(const short8*)&Os[r * 72 + c16 + 8];
}

extern "C" void kernel_launch(void* const* d_in, const int* in_sizes, int n_in,
                              void* d_out, int out_size, void* d_ws, size_t ws_size,
                              hipStream_t stream) {
  const float* x  = (const float*)d_in[0];
  const float* Wq = (const float*)d_in[1];
  const float* bq = (const float*)d_in[2];
  const float* Wk = (const float*)d_in[3];
  const float* bk = (const float*)d_in[4];
  const float* Wv = (const float*)d_in[5];
  const float* bv = (const float*)d_in[6];
  const float* Wo = (const float*)d_in[7];
  const float* bo = (const float*)d_in[8];

  short* ws = (short*)d_ws;
  short* xb       = ws;
  short* qkv      = ws + 4194304;
  short* vbuf     = qkv + 2 * 4194304;
  short* vT       = ws;            // aliases xb (dead after QKV GEMM)
  short* attn_out = vbuf;          // aliases vbuf (dead after k_tv)
  short* WT       = ws + 4 * 4194304;

  k_cast_x<<<2048, 256, 0, stream>>>(x, xb);
  k_tw<<<1024, 256, 0, stream>>>(Wq, Wk, Wv, Wo, WT);
  k_gemm256<<<192, 512, 0, stream>>>(xb, WT, bq, bk, bv, qkv);
  k_tv<<<1024, 256, 0, stream>>>(vbuf, vT);
  k_attn<<<1024, 256, 0, stream>>>(qkv, qkv + 4194304, vT, attn_out);
  {
    dim3 grid(8, 32);
    k_gemmO<<<grid, 256, 0, stream>>>(attn_out, WT + 3 * 1048576, bo, (float*)d_out);
  }
}

// Round 4
// 92.612 us; speedup vs baseline: 1.0844x; 1.0040x over previous
//
#include <hip/hip_runtime.h>
#include <cstdint>
#include <cstddef>

typedef __attribute__((ext_vector_type(8))) short short8;
typedef __attribute__((ext_vector_type(4))) short short4v;
typedef __attribute__((ext_vector_type(4))) float f32x4;
typedef __attribute__((ext_vector_type(16))) float f32x16;
typedef short8 bf16x8;

typedef __attribute__((address_space(1))) const unsigned GU;
typedef __attribute__((address_space(3))) unsigned LU;

__device__ __forceinline__ short f2bf(float f) {
  unsigned u = __builtin_bit_cast(unsigned, f);
  u += 0x7fffu + ((u >> 16) & 1u);   // RNE; inputs are finite normals
  return (short)(u >> 16);
}

// ---------------- cast x (f32 -> bf16) ----------------
__global__ __launch_bounds__(256) void k_cast_x(const float* __restrict__ x, short* __restrict__ xb) {
  size_t i = ((size_t)blockIdx.x * 256 + threadIdx.x) * 8;
  f32x4 a = *(const f32x4*)(x + i);
  f32x4 b = *(const f32x4*)(x + i + 4);
  short8 o;
#pragma unroll
  for (int j = 0; j < 4; ++j) { o[j] = f2bf(a[j]); o[4 + j] = f2bf(b[j]); }
  *(short8*)(xb + i) = o;
}

// ---------------- cast + transpose weights: WT[n][k] = W[k][n] (bf16) ----------------
__global__ __launch_bounds__(256) void k_tw(const float* __restrict__ W0, const float* __restrict__ W1,
                                            const float* __restrict__ W2, const float* __restrict__ W3,
                                            short* __restrict__ WT) {
  __shared__ short T[64 * 72];
  int bid = blockIdx.x;
  int widx = bid >> 8;
  int t = bid & 255;
  int kr = (t >> 4) * 64, nc = (t & 15) * 64;
  const float* W = widx == 0 ? W0 : widx == 1 ? W1 : widx == 2 ? W2 : W3;
  short* out = WT + (size_t)widx * 1048576;
  int tid = threadIdx.x;
#pragma unroll
  for (int i = 0; i < 4; ++i) {
    int idx = tid + i * 256;          // 1024 quads of 4 floats
    int k = idx >> 4, n4 = (idx & 15) << 2;
    f32x4 v = *(const f32x4*)(W + (size_t)(kr + k) * 1024 + nc + n4);
#pragma unroll
    for (int j = 0; j < 4; ++j) T[(n4 + j) * 72 + k] = f2bf(v[j]);
  }
  __syncthreads();
#pragma unroll
  for (int i = 0; i < 2; ++i) {
    int idx = tid + i * 256;
    int n = idx >> 3, k8 = (idx & 7) << 3;
    *(short8*)(out + (size_t)(nc + n) * 1024 + kr + k8) = *(const short8*)&T[n * 72 + k8];
  }
}

// ---------------- transpose v: vT[b][h][d][s] = v[b][s][h*64+d] ----------------
__global__ __launch_bounds__(256) void k_tv(const short* __restrict__ v, short* __restrict__ vT) {
  __shared__ short T[64 * 72];
  int bid = blockIdx.x;
  int stile = bid & 31, h = (bid >> 5) & 15, b = bid >> 9;
  int s0 = stile * 64;
  int tid = threadIdx.x;
#pragma unroll
  for (int i = 0; i < 2; ++i) {
    int idx = tid + i * 256;
    int s = idx >> 3, d0 = (idx & 7) << 3;
    short8 vec = *(const short8*)(v + ((size_t)b * 2048 + s0 + s) * 1024 + h * 64 + d0);
#pragma unroll
    for (int j = 0; j < 8; ++j) T[(d0 + j) * 72 + s] = vec[j];
  }
  __syncthreads();
#pragma unroll
  for (int i = 0; i < 2; ++i) {
    int idx = tid + i * 256;
    int d = idx >> 3, s8 = (idx & 7) << 3;
    *(short8*)(vT + (((size_t)b * 16 + h) * 64 + d) * 2048 + s0 + s8) = *(const short8*)&T[d * 72 + s8];
  }
}

// ================= 256x256 QKV GEMM, 32x32x16 MFMA, single-barrier phases =================
// C[4096,3072] = A[4096,1024] * BT[3072,1024]^T, bf16 in, fp32 acc, bf16 out (+bias).
// 512 thr = 8 waves (2M x 4N); wave out 128x64 = 4 m-frags x 2 n-frags of 32x32.
// LDS 128KB: region(buf,ab,kh) = buf*32768 + ab*16384 + kh*8192 shorts, each [256][32].
// Phase pair (buf,kh): rh0 {8 ds_read (A-frags 0,1 + all B), stage, barrier, lgkm(4),
//   4 MFMA ks0, lgkm(0), 4 MFMA ks1} ; rh1 {4 ds_read (A-frags 2,3; B reused), stage,
//   [vmcnt(4)], barrier, lgkm(2), 4 MFMA, lgkm(0), 4 MFMA}.
// ONE barrier per phase: every staged region was last READ exactly 2 barrier-positions
// earlier (reads retire before each wave's MFMA, which precedes the intervening
// barrier, so all waves' reads are retired before any wave issues the stage).
// vmcnt(4) before the barrier at phases 3/7 confirms regions >=2 phases before use.
__global__ __launch_bounds__(512, 2) void k_gemm256(
    const short* __restrict__ A, const short* __restrict__ BT,
    const float* __restrict__ bias0, const float* __restrict__ bias1, const float* __restrict__ bias2,
    short* __restrict__ outb) {
  __shared__ short S[65536];
  const int tid = threadIdx.x;
  const int lane = tid & 63, w = tid >> 6;
  const int l31 = lane & 31, hi = lane >> 5;
  const int wm = w >> 2, wn = w & 3;
  int bid = blockIdx.x;
  int swz = (bid & 7) * 24 + (bid >> 3);      // 192 = 8 XCD x 24, bijective
  const int tm = swz / 12, tn = swz % 12;
  const int m0 = tm * 256, n0 = tn * 256;
  const size_t K = 1024;
  const short* Ab = A + (size_t)m0 * K;
  const short* Bb = BT + (size_t)n0 * K;

  auto stage = [&](int roff, const short* gbase, int kt, int kh) {
    int k0 = kt * 64 + kh * 32;
#pragma unroll
    for (int i = 0; i < 2; ++i) {
      int c = tid + i * 512;
      int r = c >> 2;
      int csw = ((c & 3) ^ ((r >> 1) & 3)) << 3;   // pre-swizzled global chunk
      __builtin_amdgcn_global_load_lds((GU*)(gbase + (size_t)r * K + k0 + csw),
                                       (LU*)(&S[roff + c * 8]), 16, 0, 0);
    }
  };
  auto lda = [&](int roff, int row, int s) -> bf16x8 {
    int c = (s * 2 + hi) ^ ((row >> 1) & 3);
    return *(const bf16x8*)&S[roff + row * 32 + c * 8];
  };

  f32x16 acc[4][2];
#pragma unroll
  for (int i = 0; i < 4; ++i)
#pragma unroll
    for (int j = 0; j < 2; ++j) acc[i][j] = (f32x16)(0.0f);

#define MFA(mi, ni, av, bv) \
  acc[mi][ni] = __builtin_amdgcn_mfma_f32_32x32x16_bf16(av, bv, acc[mi][ni], 0, 0, 0)
#define VMC4 asm volatile("s_waitcnt vmcnt(4)" ::: "memory")
#define NOVM (void)0

#define GPP(buf, kh, STG0, STG1, VM1) do { \
    const int rA_ = (buf)*32768 + (kh)*8192; \
    const int rB_ = (buf)*32768 + 16384 + (kh)*8192; \
    const int ar_ = wm*128 + l31; \
    const int br_ = wn*64 + l31; \
    bf16x8 a00 = lda(rA_, ar_,      0); bf16x8 a10 = lda(rA_, ar_ + 32, 0); \
    bf16x8 b00 = lda(rB_, br_,      0); bf16x8 b10 = lda(rB_, br_ + 32, 0); \
    bf16x8 a01 = lda(rA_, ar_,      1); bf16x8 a11 = lda(rA_, ar_ + 32, 1); \
    bf16x8 b01 = lda(rB_, br_,      1); bf16x8 b11 = lda(rB_, br_ + 32, 1); \
    STG0; \
    __builtin_amdgcn_sched_barrier(0); \
    __builtin_amdgcn_s_barrier(); \
    asm volatile("s_waitcnt lgkmcnt(4)" ::: "memory"); \
    __builtin_amdgcn_sched_barrier(0); \
    __builtin_amdgcn_s_setprio(1); \
    MFA(0,0,a00,b00); MFA(0,1,a00,b10); MFA(1,0,a10,b00); MFA(1,1,a10,b10); \
    __builtin_amdgcn_sched_barrier(0); \
    asm volatile("s_waitcnt lgkmcnt(0)" ::: "memory"); \
    __builtin_amdgcn_sched_barrier(0); \
    MFA(0,0,a01,b01); MFA(0,1,a01,b11); MFA(1,0,a11,b01); MFA(1,1,a11,b11); \
    __builtin_amdgcn_s_setprio(0); \
    __builtin_amdgcn_sched_barrier(0); \
    bf16x8 c00 = lda(rA_, ar_ + 64, 0); bf16x8 c10 = lda(rA_, ar_ + 96, 0); \
    bf16x8 c01 = lda(rA_, ar_ + 64, 1); bf16x8 c11 = lda(rA_, ar_ + 96, 1); \
    STG1; \
    VM1; \
    __builtin_amdgcn_sched_barrier(0); \
    __builtin_amdgcn_s_barrier(); \
    asm volatile("s_waitcnt lgkmcnt(2)" ::: "memory"); \
    __builtin_amdgcn_sched_barrier(0); \
    __builtin_amdgcn_s_setprio(1); \
    MFA(2,0,c00,b00); MFA(2,1,c00,b10); MFA(3,0,c10,b00); MFA(3,1,c10,b10); \
    __builtin_amdgcn_sched_barrier(0); \
    asm volatile("s_waitcnt lgkmcnt(0)" ::: "memory"); \
    __builtin_amdgcn_sched_barrier(0); \
    MFA(2,0,c01,b01); MFA(2,1,c01,b11); MFA(3,0,c11,b01); MFA(3,1,c11,b11); \
    __builtin_amdgcn_s_setprio(0); \
    __builtin_amdgcn_sched_barrier(0); \
  } while (0)

  // prologue: tile0 (4 regions) + tile1 kh0 (2 regions) = 12 loads/thread
  stage(0,     Ab, 0, 0);
  stage(16384, Bb, 0, 0);
  stage(8192,  Ab, 0, 1);
  stage(24576, Bb, 0, 1);
  stage(32768, Ab, 1, 0);
  stage(49152, Bb, 1, 0);
  asm volatile("s_waitcnt vmcnt(4)" ::: "memory");   // tile0 landed
  __builtin_amdgcn_s_barrier();

  for (int j = 0; j < 8; ++j) {
    int t1 = 2 * j + 1;
    int t2 = 2 * j + 2; t2 = t2 < 15 ? t2 : 15;      // clamp: dead-region rewrite on last iter
    int t3 = 2 * j + 3; t3 = t3 < 15 ? t3 : 15;
    GPP(0, 0, stage(40960, Ab, t1, 1), stage(57344, Bb, t1, 1), NOVM);
    GPP(0, 1, stage(0,     Ab, t2, 0), stage(16384, Bb, t2, 0), VMC4);
    GPP(1, 0, stage(8192,  Ab, t2, 1), stage(24576, Bb, t2, 1), NOVM);
    GPP(1, 1, stage(32768, Ab, t3, 0), stage(49152, Bb, t3, 0), VMC4);
  }
#undef GPP
#undef MFA

  // epilogue: drain dead stages, then LDS-transpose coalesced bf16 stores
  asm volatile("s_waitcnt vmcnt(0)" ::: "memory");
  __syncthreads();
  int sel = n0 >> 10;
  const float* bias = sel == 0 ? bias0 : (sel == 1 ? bias1 : bias2);
  size_t outoff = (size_t)sel * 4194304;
  int ncol0 = n0 & 1023;
  float bv[2];
#pragma unroll
  for (int ni = 0; ni < 2; ++ni) bv[ni] = bias[ncol0 + wn * 64 + ni * 32 + l31];
  short* Ep = S;                                   // [128][264]
#pragma unroll
  for (int p = 0; p < 2; ++p) {
    __syncthreads();
#pragma unroll
    for (int mi2 = 0; mi2 < 2; ++mi2)
#pragma unroll
      for (int ni = 0; ni < 2; ++ni)
#pragma unroll
        for (int rq = 0; rq < 4; ++rq)
#pragma unroll
          for (int jj = 0; jj < 4; ++jj) {
            int rif = jj + 4 * hi + 8 * rq;        // C/D row within 32x32 frag
            Ep[(wm * 64 + mi2 * 32 + rif) * 264 + wn * 64 + ni * 32 + l31] =
                f2bf(acc[p * 2 + mi2][ni][rq * 4 + jj] + bv[ni]);
          }
    __syncthreads();
#pragma unroll
    for (int i = 0; i < 8; ++i) {
      int idx = tid + i * 512;                     // 4096 chunks of 8 bf16
      int r = idx >> 5, c8 = (idx & 31) << 3;
      int grow = m0 + (r >> 6) * 128 + p * 64 + (r & 63);
      *(short8*)&outb[outoff + (size_t)grow * 1024 + ncol0 + c8] = *(const short8*)&Ep[r * 264 + c8];
    }
  }
}

// ---------------- final GEMM (128^2): out = attn_out * WoT^T + bo ----------------
__global__ __launch_bounds__(256, 2) void k_gemmO(
    const short* __restrict__ A, const short* __restrict__ BT,
    const float* __restrict__ bias0, float* __restrict__ outf) {
  __shared__ short Smem[16384];
  const int tid = threadIdx.x;
  const int lane = tid & 63, w = tid >> 6;
  const int g = lane >> 4, qi = lane & 15;
  const int wr = (w >> 1) * 64, wc = (w & 1) * 64;
  const int m0 = blockIdx.y * 128, n0 = blockIdx.x * 128;
  const size_t K = 1024;
  const short* Ab = A + (size_t)m0 * K;
  const short* Bb = BT + (size_t)n0 * K;

  auto stage = [&](int buf, int k0) {
    short* Asb = Smem + buf * 4096;
    short* Bsb = Smem + 8192 + buf * 4096;
#pragma unroll
    for (int i = 0; i < 2; ++i) {
      int cidx = tid + i * 256;
      int r = cidx >> 2;
      int csw = ((cidx & 3) ^ ((r >> 1) & 3)) << 3;
      __builtin_amdgcn_global_load_lds((GU*)(Ab + (size_t)r * K + k0 + csw),
                                       (LU*)(&Asb[cidx * 8]), 16, 0, 0);
      __builtin_amdgcn_global_load_lds((GU*)(Bb + (size_t)r * K + k0 + csw),
                                       (LU*)(&Bsb[cidx * 8]), 16, 0, 0);
    }
  };

  f32x4 acc[4][4];
#pragma unroll
  for (int i = 0; i < 4; ++i)
#pragma unroll
    for (int j = 0; j < 4; ++j) acc[i][j] = (f32x4)(0.0f);

  stage(0, 0);
  __syncthreads();
  for (int kt = 0; kt < 32; ++kt) {
    int cur = kt & 1;
    if (kt < 31) stage(cur ^ 1, (kt + 1) * 32);
    const short* Asb = Smem + cur * 4096;
    const short* Bsb = Smem + 8192 + cur * 4096;
    bf16x8 a[4], b[4];
#pragma unroll
    for (int mf = 0; mf < 4; ++mf) {
      int R = wr + mf * 16 + qi;
      a[mf] = *(const bf16x8*)&Asb[R * 32 + ((g ^ ((R >> 1) & 3)) << 3)];
    }
#pragma unroll
    for (int nf = 0; nf < 4; ++nf) {
      int R = wc + nf * 16 + qi;
      b[nf] = *(const bf16x8*)&Bsb[R * 32 + ((g ^ ((R >> 1) & 3)) << 3)];
    }
#pragma unroll
    for (int mf = 0; mf < 4; ++mf)
#pragma unroll
      for (int nf = 0; nf < 4; ++nf)
        acc[mf][nf] = __builtin_amdgcn_mfma_f32_16x16x32_bf16(a[mf], b[nf], acc[mf][nf], 0, 0, 0);
    __syncthreads();
  }

  float* Ft = (float*)Smem;                  // [32][136]
  float bv[4];
#pragma unroll
  for (int nf = 0; nf < 4; ++nf) bv[nf] = bias0[n0 + wc + nf * 16 + qi];
#pragma unroll
  for (int mf = 0; mf < 4; ++mf) {
    __syncthreads();
#pragma unroll
    for (int nf = 0; nf < 4; ++nf)
#pragma unroll
      for (int j = 0; j < 4; ++j)
        Ft[((w >> 1) * 16 + g * 4 + j) * 136 + wc + nf * 16 + qi] = acc[mf][nf][j] + bv[nf];
    __syncthreads();
#pragma unroll
    for (int i = 0; i < 4; ++i) {
      int idx = tid + i * 256;
      int r = idx >> 5, c4 = (idx & 31) << 2;
      int row = m0 + ((r >> 4) << 6) + mf * 16 + (r & 15);
      *(f32x4*)&outf[(size_t)row * 1024 + n0 + c4] = *(const f32x4*)&Ft[r * 136 + c4];
    }
  }
}

// ---------------- banded flash attention ----------------
__global__ __launch_bounds__(256, 2) void k_attn(const short* __restrict__ qg_,
                                                 const short* __restrict__ kg_,
                                                 const short* __restrict__ vT,
                                                 short* __restrict__ outp) {
  __shared__ short Qs[64 * 72];
  __shared__ short Ks[64 * 72];
  __shared__ short Vs[64 * 72];
  __shared__ short Ps[4][16 * 72];
  int bid = blockIdx.x;
  int qt = bid & 31, h = (bid >> 5) & 15, b = bid >> 9;
  int q0 = qt * 64;
  int tid = threadIdx.x, lane = tid & 63, w = tid >> 6;
  int g = lane >> 4, qi = lane & 15;

  const short* qsrc = qg_ + ((size_t)b * 2048 + q0) * 1024 + h * 64;
#pragma unroll
  for (int i = 0; i < 2; ++i) {
    int idx = tid + i * 256;
    int r = idx >> 3, c = (idx & 7) << 3;
    *(short8*)&Qs[r * 72 + c] = *(const short8*)&qsrc[(size_t)r * 1024 + c];
  }

  float m = -1e30f, l = 0.f;
  f32x4 oacc[4];
#pragma unroll
  for (int i = 0; i < 4; ++i) oacc[i] = (f32x4)(0.0f);
  int qglob = q0 + w * 16 + qi;

  for (int cc = 0; cc < 5; ++cc) {
    int kb0 = q0 - 128 + cc * 64;
    if (kb0 < 0 || kb0 >= 2048) continue;
    __syncthreads();
    const short* ksrc = kg_ + ((size_t)b * 2048 + kb0) * 1024 + h * 64;
    const short* vsrc = vT + ((size_t)(b * 16 + h)) * 64 * 2048 + kb0;
#pragma unroll
    for (int i = 0; i < 2; ++i) {
      int idx = tid + i * 256;
      int r = idx >> 3, c = (idx & 7) << 3;
      *(short8*)&Ks[r * 72 + c] = *(const short8*)&ksrc[(size_t)r * 1024 + c];
      *(short8*)&Vs[r * 72 + c] = *(const short8*)&vsrc[(size_t)r * 2048 + c];
    }
    __syncthreads();

    f32x4 st[4];
#pragma unroll
    for (int i = 0; i < 4; ++i) st[i] = (f32x4)(0.0f);
#pragma unroll
    for (int ds = 0; ds < 2; ++ds) {
      bf16x8 qf = *(const bf16x8*)&Qs[(w * 16 + qi) * 72 + ds * 32 + g * 8];
#pragma unroll
      for (int mf = 0; mf < 4; ++mf) {
        bf16x8 kf = *(const bf16x8*)&Ks[(mf * 16 + qi) * 72 + ds * 32 + g * 8];
        st[mf] = __builtin_amdgcn_mfma_f32_16x16x32_bf16(kf, qf, st[mf], 0, 0, 0);
      }
    }

    float pv[16];
    float pm = -1e30f;
#pragma unroll
    for (int mf = 0; mf < 4; ++mf)
#pragma unroll
      for (int j = 0; j < 4; ++j) {
        int kcol = kb0 + mf * 16 + g * 4 + j;
        float s = st[mf][j] * 0.125f;
        int d = kcol - qglob;
        bool valid = (d >= -128) && (d <= 128);
        s = valid ? s : -1e30f;
        pv[mf * 4 + j] = s;
        pm = fmaxf(pm, s);
      }
    pm = fmaxf(pm, __shfl_xor(pm, 16));
    pm = fmaxf(pm, __shfl_xor(pm, 32));
    float mnew = fmaxf(m, pm);
    float scale = __expf(m - mnew);
    float ls = 0.f;
#pragma unroll
    for (int e = 0; e < 16; ++e) {
      float p = pv[e] > -1e29f ? __expf(pv[e] - mnew) : 0.f;
      pv[e] = p;
      ls += p;
    }
    ls += __shfl_xor(ls, 16);
    ls += __shfl_xor(ls, 32);
    l = l * scale + ls;
    m = mnew;
#pragma unroll
    for (int mf = 0; mf < 4; ++mf) oacc[mf] *= scale;

#pragma unroll
    for (int f = 0; f < 4; ++f) {
      short4v pk;
#pragma unroll
      for (int j = 0; j < 4; ++j) pk[j] = f2bf(pv[f * 4 + j]);
      *(short4v*)&Ps[w][qi * 72 + f * 16 + g * 4] = pk;
    }

#pragma unroll
    for (int ks = 0; ks < 2; ++ks) {
      bf16x8 pf = *(const bf16x8*)&Ps[w][qi * 72 + ks * 32 + g * 8];
#pragma unroll
      for (int mf = 0; mf < 4; ++mf) {
        bf16x8 vf = *(const bf16x8*)&Vs[(mf * 16 + qi) * 72 + ks * 32 + g * 8];
        oacc[mf] = __builtin_amdgcn_mfma_f32_16x16x32_bf16(vf, pf, oacc[mf], 0, 0, 0);
      }
    }
  }

  __syncthreads();
  short* Os = Ks;
  float inv = 1.f / l;
#pragma unroll
  for (int mf = 0; mf < 4; ++mf) {
    short4v pk;
#pragma unroll
    for (int j = 0; j < 4; ++j) pk[j] = f2bf(oacc[mf][j] * inv);
    *(short4v*)&Os[(w * 16 + qi) * 72 + mf * 16 + g * 4] = pk;
  }
  __syncthreads();
  short* dst = outp + ((size_t)b * 2048 + q0) * 1024 + h * 64;
  int r = tid >> 2, c16 = (tid & 3) << 4;
  *(short8*)&dst[(size_t)r * 1024 + c16] = *(const short8*)&Os[r * 72 + c16];
  *(short8*)&dst[(size_t)r * 1024 + c16 + 8] = *(const short8*)&Os[r * 72 + c16 + 8];
}

extern "C" void kernel_launch(void* const* d_in, const int* in_sizes, int n_in,
                              void* d_out, int out_size, void* d_ws, size_t ws_size,
                              hipStream_t stream) {
  const float* x  = (const float*)d_in[0];
  const float* Wq = (const float*)d_in[1];
  const float* bq = (const float*)d_in[2];
  const float* Wk = (const float*)d_in[3];
  const float* bk = (const float*)d_in[4];
  const float* Wv = (const float*)d_in[5];
  const float* bv = (const float*)d_in[6];
  const float* Wo = (const float*)d_in[7];
  const float* bo = (const float*)d_in[8];

  short* ws = (short*)d_ws;
  short* xb       = ws;
  short* qkv      = ws + 4194304;
  short* vbuf     = qkv + 2 * 4194304;
  short* vT       = ws;            // aliases xb (dead after QKV GEMM)
  short* attn_out = vbuf;          // aliases vbuf (dead after k_tv)
  short* WT       = ws + 4 * 4194304;

  k_cast_x<<<2048, 256, 0, stream>>>(x, xb);
  k_tw<<<1024, 256, 0, stream>>>(Wq, Wk, Wv, Wo, WT);
  k_gemm256<<<192, 512, 0, stream>>>(xb, WT, bq, bk, bv, qkv);
  k_tv<<<1024, 256, 0, stream>>>(vbuf, vT);
  k_attn<<<1024, 256, 0, stream>>>(qkv, qkv + 4194304, vT, attn_out);
  {
    dim3 grid(8, 32);
    k_gemmO<<<grid, 256, 0, stream>>>(attn_out, WT + 3 * 1048576, bo, (float*)d_out);
  }
}

// Round 5
// 90.003 us; speedup vs baseline: 1.1159x; 1.0290x over previous
//
#include <hip/hip_runtime.h>
#include <cstdint>
#include <cstddef>

typedef __attribute__((ext_vector_type(8))) short short8;
typedef __attribute__((ext_vector_type(4))) short short4v;
typedef __attribute__((ext_vector_type(4))) float f32x4;
typedef short8 bf16x8;

typedef __attribute__((address_space(1))) const unsigned GU;
typedef __attribute__((address_space(3))) unsigned LU;

__device__ __forceinline__ short f2bf(float f) {
  unsigned u = __builtin_bit_cast(unsigned, f);
  u += 0x7fffu + ((u >> 16) & 1u);   // RNE; inputs are finite normals
  return (short)(u >> 16);
}

// ---------------- cast x (f32 -> bf16) ----------------
__global__ __launch_bounds__(256) void k_cast_x(const float* __restrict__ x, short* __restrict__ xb) {
  size_t i = ((size_t)blockIdx.x * 256 + threadIdx.x) * 8;
  f32x4 a = *(const f32x4*)(x + i);
  f32x4 b = *(const f32x4*)(x + i + 4);
  short8 o;
#pragma unroll
  for (int j = 0; j < 4; ++j) { o[j] = f2bf(a[j]); o[4 + j] = f2bf(b[j]); }
  *(short8*)(xb + i) = o;
}

// ---------------- cast + transpose weights: WT[n][k] = W[k][n] (bf16) ----------------
__global__ __launch_bounds__(256) void k_tw(const float* __restrict__ W0, const float* __restrict__ W1,
                                            const float* __restrict__ W2, const float* __restrict__ W3,
                                            short* __restrict__ WT) {
  __shared__ short T[64 * 72];
  int bid = blockIdx.x;
  int widx = bid >> 8;
  int t = bid & 255;
  int kr = (t >> 4) * 64, nc = (t & 15) * 64;
  const float* W = widx == 0 ? W0 : widx == 1 ? W1 : widx == 2 ? W2 : W3;
  short* out = WT + (size_t)widx * 1048576;
  int tid = threadIdx.x;
#pragma unroll
  for (int i = 0; i < 4; ++i) {
    int idx = tid + i * 256;          // 1024 quads of 4 floats
    int k = idx >> 4, n4 = (idx & 15) << 2;
    f32x4 v = *(const f32x4*)(W + (size_t)(kr + k) * 1024 + nc + n4);
#pragma unroll
    for (int j = 0; j < 4; ++j) T[(n4 + j) * 72 + k] = f2bf(v[j]);
  }
  __syncthreads();
#pragma unroll
  for (int i = 0; i < 2; ++i) {
    int idx = tid + i * 256;
    int n = idx >> 3, k8 = (idx & 7) << 3;
    *(short8*)(out + (size_t)(nc + n) * 1024 + kr + k8) = *(const short8*)&T[n * 72 + k8];
  }
}

// ---------------- transpose v: vT[b][h][d][s] = v[b][s][h*64+d] ----------------
__global__ __launch_bounds__(256) void k_tv(const short* __restrict__ v, short* __restrict__ vT) {
  __shared__ short T[64 * 72];
  int bid = blockIdx.x;
  int stile = bid & 31, h = (bid >> 5) & 15, b = bid >> 9;
  int s0 = stile * 64;
  int tid = threadIdx.x;
#pragma unroll
  for (int i = 0; i < 2; ++i) {
    int idx = tid + i * 256;
    int s = idx >> 3, d0 = (idx & 7) << 3;
    short8 vec = *(const short8*)(v + ((size_t)b * 2048 + s0 + s) * 1024 + h * 64 + d0);
#pragma unroll
    for (int j = 0; j < 8; ++j) T[(d0 + j) * 72 + s] = vec[j];
  }
  __syncthreads();
#pragma unroll
  for (int i = 0; i < 2; ++i) {
    int idx = tid + i * 256;
    int d = idx >> 3, s8 = (idx & 7) << 3;
    *(short8*)(vT + (((size_t)b * 16 + h) * 64 + d) * 2048 + s0 + s8) = *(const short8*)&T[d * 72 + s8];
  }
}

// ================= 256x256 QKV GEMM — row-split half-tiles, dead-region rotation ==========
// C[4096,3072] = A[4096,1024] * BT[3072,1024]^T, bf16 in, fp32 acc, bf16 out (+bias).
// 512 thr = 8 waves (wm=w>>2 in {0,1}: 128 rows; wn=w&3: 64 cols). 16x16x32 MFMA,
// acc[8][4] f32x4. BK=64 per K-tile, kk in {0,1} 32-wide.
// LDS: reg(b,which) = b*32768 + which*8192 shorts; which: 0=Ah0(rows0-127) 1=Ah1 2=Bh0(cols0-127) 3=Bh1.
// Swizzle: LDS chunk cc holds global chunk (cc&7)^(row&7); read XORs the same (uniform bank-quad spread).
// Per K-tile T (buf b=T&1):
//  ph0: stage (T+1).Ah0->reg(nb,0); read A-kk0[mf0-3], B-kk0, A-kk0[mf4-7]; lgkm(4); MFMA kk0 x mf0-3.
//  ph1: stage (T+1).Ah1->reg(nb,1); read A-kk1[mf0-3], B-kk1, A-kk1[mf4-7]; lgkm(12); MFMA kk0 x mf4-7; BARRIER.
//  ph2: stage (T+2).Bh0->reg(b,2);  lgkm(4); MFMA kk1 x mf0-3.
//  ph3: stage (T+2).Bh1->reg(b,3);  vmcnt(4); lgkm(0); MFMA kk1 x mf4-7; BARRIER.
// Liveness: A regions dead after ph1 (A read only ph0/ph1, reg-cached); B regions dead after ph1
// (B-kk1 read at ph1). (T+1).Ah* stages hit regions last read at T-1.ph0/1 (2 barriers back);
// (T+2).Bh* stages hit regions whose reads ended before the ph1 barrier. All stage leads >=3 phases.
// vmcnt(4) at ph3 drains prior-tile ph2/3 + this-tile ph0/1 stages => T+1 fully landed; leaves
// this ph2/3 (2 half-tiles) in flight. Last iters clamp stage tiles to 15 (dead/same-data rewrites).
__global__ __launch_bounds__(512, 2) void k_gemm256(
    const short* __restrict__ A, const short* __restrict__ BT,
    const float* __restrict__ bias0, const float* __restrict__ bias1, const float* __restrict__ bias2,
    short* __restrict__ outb) {
  __shared__ short S[65536];
  const int tid = threadIdx.x;
  const int lane = tid & 63, w = tid >> 6;
  const int g = lane >> 4, qi = lane & 15;
  const int wm = w >> 2, wn = w & 3;
  int bid = blockIdx.x;
  int swz = (bid & 7) * 24 + (bid >> 3);      // 192 = 8 XCD x 24, bijective
  const int tm = swz / 12, tn = swz % 12;
  const int m0 = tm * 256, n0 = tn * 256;
  const size_t K = 1024;
  const short* Ab = A + (size_t)m0 * K;
  const short* Bb = BT + (size_t)n0 * K;

  auto stage = [&](int roff, const short* gbase, int kt) {
#pragma unroll
    for (int i = 0; i < 2; ++i) {
      int cc = tid + i * 512;                 // 1024 chunks of 16B per 128x64 half-tile
      int r = cc >> 3;
      int js = ((cc & 7) ^ (r & 7)) << 3;     // pre-swizzled global chunk
      __builtin_amdgcn_global_load_lds((GU*)(gbase + (size_t)r * K + kt * 64 + js),
                                       (LU*)(&S[roff + cc * 8]), 16, 0, 0);
    }
  };
  auto lda = [&](int roff, int row, int kk) -> bf16x8 {
    return *(const bf16x8*)&S[roff + row * 64 + (((kk * 4 + g) ^ (row & 7)) << 3)];
  };

  f32x4 acc[8][4];
#pragma unroll
  for (int i = 0; i < 8; ++i)
#pragma unroll
    for (int j = 0; j < 4; ++j) acc[i][j] = (f32x4)(0.0f);

#define MFA(mi, ni, av, bv) \
  acc[mi][ni] = __builtin_amdgcn_mfma_f32_16x16x32_bf16(av, bv, acc[mi][ni], 0, 0, 0)
#define SB __builtin_amdgcn_sched_barrier(0)

  // prologue: T0 all 4 halves + T1.Bh0/Bh1
  stage(0,     Ab,          0);
  stage(8192,  Ab + 131072, 0);
  stage(16384, Bb,          0);
  stage(24576, Bb + 131072, 0);
  stage(49152, Bb,          1);
  stage(57344, Bb + 131072, 1);
  asm volatile("s_waitcnt vmcnt(4)" ::: "memory");   // T0 landed; T1.Bh* in flight
  __builtin_amdgcn_s_barrier();

  for (int t = 0; t < 16; ++t) {
    const int b = t & 1, nb = b ^ 1;
    const int rA = b * 32768 + wm * 8192;
    const int rB = b * 32768 + 16384 + (wn >> 1) * 8192;
    const int brow = (wn & 1) * 64;
    const int t1 = t + 1 < 15 ? t + 1 : 15;
    const int t2 = t + 2 < 15 ? t + 2 : 15;
    bf16x8 aA[8], aB[4], cA[8], cB[4];

    // ---- ph0 ----
    stage(nb * 32768, Ab, t1);                         // (T+1).Ah0
#pragma unroll
    for (int mf = 0; mf < 4; ++mf) aA[mf] = lda(rA, mf * 16 + qi, 0);
#pragma unroll
    for (int nf = 0; nf < 4; ++nf) aB[nf] = lda(rB, brow + nf * 16 + qi, 0);
    SB;                                                // pin read-group order for lgkm counts
#pragma unroll
    for (int mf = 4; mf < 8; ++mf) aA[mf] = lda(rA, mf * 16 + qi, 0);
    asm volatile("s_waitcnt lgkmcnt(4)" ::: "memory");
    SB;
    __builtin_amdgcn_s_setprio(1);
#pragma unroll
    for (int mf = 0; mf < 4; ++mf)
#pragma unroll
      for (int nf = 0; nf < 4; ++nf) MFA(mf, nf, aA[mf], aB[nf]);
    __builtin_amdgcn_s_setprio(0);
    SB;
    // ---- ph1 ----
    stage(nb * 32768 + 8192, Ab + 131072, t1);         // (T+1).Ah1
#pragma unroll
    for (int mf = 0; mf < 4; ++mf) cA[mf] = lda(rA, mf * 16 + qi, 1);
#pragma unroll
    for (int nf = 0; nf < 4; ++nf) cB[nf] = lda(rB, brow + nf * 16 + qi, 1);
    SB;
#pragma unroll
    for (int mf = 4; mf < 8; ++mf) cA[mf] = lda(rA, mf * 16 + qi, 1);
    asm volatile("s_waitcnt lgkmcnt(12)" ::: "memory");
    SB;
    __builtin_amdgcn_s_setprio(1);
#pragma unroll
    for (int mf = 4; mf < 8; ++mf)
#pragma unroll
      for (int nf = 0; nf < 4; ++nf) MFA(mf, nf, aA[mf], aB[nf]);
    __builtin_amdgcn_s_setprio(0);
    SB;
    __builtin_amdgcn_s_barrier();                      // end-ph1: all T-region ds_reads issued
    // ---- ph2 ----
    stage(b * 32768 + 16384, Bb, t2);                  // (T+2).Bh0
    asm volatile("s_waitcnt lgkmcnt(4)" ::: "memory");
    SB;
    __builtin_amdgcn_s_setprio(1);
#pragma unroll
    for (int mf = 0; mf < 4; ++mf)
#pragma unroll
      for (int nf = 0; nf < 4; ++nf) MFA(mf, nf, cA[mf], cB[nf]);
    __builtin_amdgcn_s_setprio(0);
    SB;
    // ---- ph3 ----
    stage(b * 32768 + 24576, Bb + 131072, t2);         // (T+2).Bh1
    asm volatile("s_waitcnt vmcnt(4)" ::: "memory");   // T+1 fully landed; 2 half-tiles in flight
    asm volatile("s_waitcnt lgkmcnt(0)" ::: "memory");
    SB;
    __builtin_amdgcn_s_setprio(1);
#pragma unroll
    for (int mf = 4; mf < 8; ++mf)
#pragma unroll
      for (int nf = 0; nf < 4; ++nf) MFA(mf, nf, cA[mf], cB[nf]);
    __builtin_amdgcn_s_setprio(0);
    SB;
    __builtin_amdgcn_s_barrier();                      // end-ph3 (after vmcnt): T+1 readable
  }
#undef MFA
#undef SB

  // epilogue: drain clamped stages, then LDS-transpose coalesced bf16 stores
  asm volatile("s_waitcnt vmcnt(0)" ::: "memory");
  __syncthreads();
  int sel = n0 >> 10;
  const float* bias = sel == 0 ? bias0 : (sel == 1 ? bias1 : bias2);
  size_t outoff = (size_t)sel * 4194304;
  int ncol0 = n0 & 1023;
  float bv[4];
#pragma unroll
  for (int nf = 0; nf < 4; ++nf) bv[nf] = bias[ncol0 + wn * 64 + nf * 16 + qi];
  short* Ep = S;                                       // [128][264]
#pragma unroll
  for (int p = 0; p < 2; ++p) {
    __syncthreads();
    if (wm == p) {
#pragma unroll
      for (int mf = 0; mf < 8; ++mf)
#pragma unroll
        for (int nf = 0; nf < 4; ++nf)
#pragma unroll
          for (int j = 0; j < 4; ++j)
            Ep[(mf * 16 + g * 4 + j) * 264 + wn * 64 + nf * 16 + qi] =
                f2bf(acc[mf][nf][j] + bv[nf]);
    }
    __syncthreads();
#pragma unroll
    for (int i = 0; i < 8; ++i) {
      int idx = tid + i * 512;                         // 4096 chunks of 8 bf16
      int r = idx >> 5, c8 = (idx & 31) << 3;
      int grow = m0 + p * 128 + r;
      *(short8*)&outb[outoff + (size_t)grow * 1024 + ncol0 + c8] = *(const short8*)&Ep[r * 264 + c8];
    }
  }
}

// ---------------- final GEMM (128^2): out = attn_out * WoT^T + bo ----------------
__global__ __launch_bounds__(256, 2) void k_gemmO(
    const short* __restrict__ A, const short* __restrict__ BT,
    const float* __restrict__ bias0, float* __restrict__ outf) {
  __shared__ short Smem[16384];
  const int tid = threadIdx.x;
  const int lane = tid & 63, w = tid >> 6;
  const int g = lane >> 4, qi = lane & 15;
  const int wr = (w >> 1) * 64, wc = (w & 1) * 64;
  const int m0 = blockIdx.y * 128, n0 = blockIdx.x * 128;
  const size_t K = 1024;
  const short* Ab = A + (size_t)m0 * K;
  const short* Bb = BT + (size_t)n0 * K;

  auto stage = [&](int buf, int k0) {
    short* Asb = Smem + buf * 4096;
    short* Bsb = Smem + 8192 + buf * 4096;
#pragma unroll
    for (int i = 0; i < 2; ++i) {
      int cidx = tid + i * 256;
      int r = cidx >> 2;
      int csw = ((cidx & 3) ^ ((r >> 1) & 3)) << 3;
      __builtin_amdgcn_global_load_lds((GU*)(Ab + (size_t)r * K + k0 + csw),
                                       (LU*)(&Asb[cidx * 8]), 16, 0, 0);
      __builtin_amdgcn_global_load_lds((GU*)(Bb + (size_t)r * K + k0 + csw),
                                       (LU*)(&Bsb[cidx * 8]), 16, 0, 0);
    }
  };

  f32x4 acc[4][4];
#pragma unroll
  for (int i = 0; i < 4; ++i)
#pragma unroll
    for (int j = 0; j < 4; ++j) acc[i][j] = (f32x4)(0.0f);

  stage(0, 0);
  __syncthreads();
  for (int kt = 0; kt < 32; ++kt) {
    int cur = kt & 1;
    if (kt < 31) stage(cur ^ 1, (kt + 1) * 32);
    const short* Asb = Smem + cur * 4096;
    const short* Bsb = Smem + 8192 + cur * 4096;
    bf16x8 a[4], b[4];
#pragma unroll
    for (int mf = 0; mf < 4; ++mf) {
      int R = wr + mf * 16 + qi;
      a[mf] = *(const bf16x8*)&Asb[R * 32 + ((g ^ ((R >> 1) & 3)) << 3)];
    }
#pragma unroll
    for (int nf = 0; nf < 4; ++nf) {
      int R = wc + nf * 16 + qi;
      b[nf] = *(const bf16x8*)&Bsb[R * 32 + ((g ^ ((R >> 1) & 3)) << 3)];
    }
#pragma unroll
    for (int mf = 0; mf < 4; ++mf)
#pragma unroll
      for (int nf = 0; nf < 4; ++nf)
        acc[mf][nf] = __builtin_amdgcn_mfma_f32_16x16x32_bf16(a[mf], b[nf], acc[mf][nf], 0, 0, 0);
    __syncthreads();
  }

  float* Ft = (float*)Smem;                  // [32][136]
  float bv[4];
#pragma unroll
  for (int nf = 0; nf < 4; ++nf) bv[nf] = bias0[n0 + wc + nf * 16 + qi];
#pragma unroll
  for (int mf = 0; mf < 4; ++mf) {
    __syncthreads();
#pragma unroll
    for (int nf = 0; nf < 4; ++nf)
#pragma unroll
      for (int j = 0; j < 4; ++j)
        Ft[((w >> 1) * 16 + g * 4 + j) * 136 + wc + nf * 16 + qi] = acc[mf][nf][j] + bv[nf];
    __syncthreads();
#pragma unroll
    for (int i = 0; i < 4; ++i) {
      int idx = tid + i * 256;
      int r = idx >> 5, c4 = (idx & 31) << 2;
      int row = m0 + ((r >> 4) << 6) + mf * 16 + (r & 15);
      *(f32x4*)&outf[(size_t)row * 1024 + n0 + c4] = *(const f32x4*)&Ft[r * 136 + c4];
    }
  }
}

// ---------------- banded flash attention ----------------
__global__ __launch_bounds__(256, 2) void k_attn(const short* __restrict__ qg_,
                                                 const short* __restrict__ kg_,
                                                 const short* __restrict__ vT,
                                                 short* __restrict__ outp) {
  __shared__ short Qs[64 * 72];
  __shared__ short Ks[64 * 72];
  __shared__ short Vs[64 * 72];
  __shared__ short Ps[4][16 * 72];
  int bid = blockIdx.x;
  int qt = bid & 31, h = (bid >> 5) & 15, b = bid >> 9;
  int q0 = qt * 64;
  int tid = threadIdx.x, lane = tid & 63, w = tid >> 6;
  int g = lane >> 4, qi = lane & 15;

  const short* qsrc = qg_ + ((size_t)b * 2048 + q0) * 1024 + h * 64;
#pragma unroll
  for (int i = 0; i < 2; ++i) {
    int idx = tid + i * 256;
    int r = idx >> 3, c = (idx & 7) << 3;
    *(short8*)&Qs[r * 72 + c] = *(const short8*)&qsrc[(size_t)r * 1024 + c];
  }

  float m = -1e30f, l = 0.f;
  f32x4 oacc[4];
#pragma unroll
  for (int i = 0; i < 4; ++i) oacc[i] = (f32x4)(0.0f);
  int qglob = q0 + w * 16 + qi;

  for (int cc = 0; cc < 5; ++cc) {
    int kb0 = q0 - 128 + cc * 64;
    if (kb0 < 0 || kb0 >= 2048) continue;
    __syncthreads();
    const short* ksrc = kg_ + ((size_t)b * 2048 + kb0) * 1024 + h * 64;
    const short* vsrc = vT + ((size_t)(b * 16 + h)) * 64 * 2048 + kb0;
#pragma unroll
    for (int i = 0; i < 2; ++i) {
      int idx = tid + i * 256;
      int r = idx >> 3, c = (idx & 7) << 3;
      *(short8*)&Ks[r * 72 + c] = *(const short8*)&ksrc[(size_t)r * 1024 + c];
      *(short8*)&Vs[r * 72 + c] = *(const short8*)&vsrc[(size_t)r * 2048 + c];
    }
    __syncthreads();

    f32x4 st[4];
#pragma unroll
    for (int i = 0; i < 4; ++i) st[i] = (f32x4)(0.0f);
#pragma unroll
    for (int ds = 0; ds < 2; ++ds) {
      bf16x8 qf = *(const bf16x8*)&Qs[(w * 16 + qi) * 72 + ds * 32 + g * 8];
#pragma unroll
      for (int mf = 0; mf < 4; ++mf) {
        bf16x8 kf = *(const bf16x8*)&Ks[(mf * 16 + qi) * 72 + ds * 32 + g * 8];
        st[mf] = __builtin_amdgcn_mfma_f32_16x16x32_bf16(kf, qf, st[mf], 0, 0, 0);
      }
    }

    float pv[16];
    float pm = -1e30f;
#pragma unroll
    for (int mf = 0; mf < 4; ++mf)
#pragma unroll
      for (int j = 0; j < 4; ++j) {
        int kcol = kb0 + mf * 16 + g * 4 + j;
        float s = st[mf][j] * 0.125f;
        int d = kcol - qglob;
        bool valid = (d >= -128) && (d <= 128);
        s = valid ? s : -1e30f;
        pv[mf * 4 + j] = s;
        pm = fmaxf(pm, s);
      }
    pm = fmaxf(pm, __shfl_xor(pm, 16));
    pm = fmaxf(pm, __shfl_xor(pm, 32));
    float mnew = fmaxf(m, pm);
    float scale = __expf(m - mnew);
    float ls = 0.f;
#pragma unroll
    for (int e = 0; e < 16; ++e) {
      float p = pv[e] > -1e29f ? __expf(pv[e] - mnew) : 0.f;
      pv[e] = p;
      ls += p;
    }
    ls += __shfl_xor(ls, 16);
    ls += __shfl_xor(ls, 32);
    l = l * scale + ls;
    m = mnew;
#pragma unroll
    for (int mf = 0; mf < 4; ++mf) oacc[mf] *= scale;

#pragma unroll
    for (int f = 0; f < 4; ++f) {
      short4v pk;
#pragma unroll
      for (int j = 0; j < 4; ++j) pk[j] = f2bf(pv[f * 4 + j]);
      *(short4v*)&Ps[w][qi * 72 + f * 16 + g * 4] = pk;
    }

#pragma unroll
    for (int ks = 0; ks < 2; ++ks) {
      bf16x8 pf = *(const bf16x8*)&Ps[w][qi * 72 + ks * 32 + g * 8];
#pragma unroll
      for (int mf = 0; mf < 4; ++mf) {
        bf16x8 vf = *(const bf16x8*)&Vs[(mf * 16 + qi) * 72 + ks * 32 + g * 8];
        oacc[mf] = __builtin_amdgcn_mfma_f32_16x16x32_bf16(vf, pf, oacc[mf], 0, 0, 0);
      }
    }
  }

  __syncthreads();
  short* Os = Ks;
  float inv = 1.f / l;
#pragma unroll
  for (int mf = 0; mf < 4; ++mf) {
    short4v pk;
#pragma unroll
    for (int j = 0; j < 4; ++j) pk[j] = f2bf(oacc[mf][j] * inv);
    *(short4v*)&Os[(w * 16 + qi) * 72 + mf * 16 + g * 4] = pk;
  }
  __syncthreads();
  short* dst = outp + ((size_t)b * 2048 + q0) * 1024 + h * 64;
  int r = tid >> 2, c16 = (tid & 3) << 4;
  *(short8*)&dst[(size_t)r * 1024 + c16] = *(const short8*)&Os[r * 72 + c16];
  *(short8*)&dst[(size_t)r * 1024 + c16 + 8] = *(const short8*)&Os[r * 72 + c16 + 8];
}

extern "C" void kernel_launch(void* const* d_in, const int* in_sizes, int n_in,
                              void* d_out, int out_size, void* d_ws, size_t ws_size,
                              hipStream_t stream) {
  const float* x  = (const float*)d_in[0];
  const float* Wq = (const float*)d_in[1];
  const float* bq = (const float*)d_in[2];
  const float* Wk = (const float*)d_in[3];
  const float* bk = (const float*)d_in[4];
  const float* Wv = (const float*)d_in[5];
  const float* bv = (const float*)d_in[6];
  const float* Wo = (const float*)d_in[7];
  const float* bo = (const float*)d_in[8];

  short* ws = (short*)d_ws;
  short* xb       = ws;
  short* qkv      = ws + 4194304;
  short* vbuf     = qkv + 2 * 4194304;
  short* vT       = ws;            // aliases xb (dead after QKV GEMM)
  short* attn_out = vbuf;          // aliases vbuf (dead after k_tv)
  short* WT       = ws + 4 * 4194304;

  k_cast_x<<<2048, 256, 0, stream>>>(x, xb);
  k_tw<<<1024, 256, 0, stream>>>(Wq, Wk, Wv, Wo, WT);
  k_gemm256<<<192, 512, 0, stream>>>(xb, WT, bq, bk, bv, qkv);
  k_tv<<<1024, 256, 0, stream>>>(vbuf, vT);
  k_attn<<<1024, 256, 0, stream>>>(qkv, qkv + 4194304, vT, attn_out);
  {
    dim3 grid(8, 32);
    k_gemmO<<<grid, 256, 0, stream>>>(attn_out, WT + 3 * 1048576, bo, (float*)d_out);
  }
}